// Round 1
// 7898.482 us; speedup vs baseline: 1.4403x; 1.4403x over previous
//
#include <hip/hip_runtime.h>

// Pointer network: encoder LSTM -> enc_proj -> decoder LSTM + attention argmax.
// B=512, S=100, D=2, H=256.
//
// NUMERICS (FROZEN since R7, absmax 7.0 <= 7.2): f64 state trajectory (h/c/
// gates/ep/dp in f64; chain ORDER may vary -- error ~1e-13 << decision gaps)
// + EXACT np-faithful fp32 log_softmax selection (single f32 rounding of
// scores, pairwise-8 sum of exps, lp=fl(fl(s-m)-L), argmax(lp) first-index,
// lp_acc sequential fp32). Selection block below is byte-identical to R7-R12.
//
// R12: barrier-free, one block per batch element (thread = hidden unit).
// R13: attention-score restructure.
//  (a) unmasked-s list distributed round-robin over the 4 waves; each lane
//      covers a 4-u quad -> ONE 64-lane butterfly yields the full 256-u sum.
//      Butterfly count 4x down, sred[s][4] combine eliminated, ep reads are
//      32B/lane double2 pairs, dp/Vw hoisted to loop-invariant registers.
//  (b) branch-free f64 tanh (Cody-Waite exp + rcp_f64/NR division) in the
//      SCORE path only; abs err <~5e-16, inside the blessed 1e-13 f64-chain
//      class. LSTM cells keep libm transcendentals (frozen trajectory).

#define B_WHE  0ull                       // f32 [256 k][256 u][4 g] enc Whh^T
#define B_WHD  (B_WHE + 1048576ull)       // f32 dec
#define B_WET  (B_WHD + 1048576ull)       // f32 [256 k][256 u] We^T
#define B_WDT  (B_WET + 262144ull)        // Wd^T
#define B_WXE  (B_WDT + 262144ull)        // f64 [256 u][16] Wih+bias pack
#define B_WXD  (B_WXE + 32768ull)
#define B_EP   (B_WXD + 32768ull)         // f64 [512 b][100 t][256 u] = 104.9MB

__device__ __forceinline__ double sigmoid_d(double x) {
  return 1.0 / (1.0 + exp(-x));
}

// ---------- R13 branch-free f64 tanh (attention scores only) ----------
__device__ __forceinline__ double exp_pos_d(double a) {  // a in [0, 45]
  const double L2E    = 1.4426950408889634074;
  const double LN2_HI = 6.9314718036912381649e-01;   // ln2 hi (20 low bits 0)
  const double LN2_LO = 1.9082149292705877000e-10;
  const double nf = rint(a * L2E);
  double t = __builtin_fma(-nf, LN2_HI, a);
  t = __builtin_fma(-nf, LN2_LO, t);
  double p = 2.0876756987868099e-09;                 // 1/12!
  p = __builtin_fma(p, t, 2.5052108385441720e-08);   // 1/11!
  p = __builtin_fma(p, t, 2.7557319223985888e-07);
  p = __builtin_fma(p, t, 2.7557319223985893e-06);
  p = __builtin_fma(p, t, 2.4801587301587302e-05);
  p = __builtin_fma(p, t, 1.9841269841269841e-04);
  p = __builtin_fma(p, t, 1.3888888888888889e-03);
  p = __builtin_fma(p, t, 8.3333333333333332e-03);
  p = __builtin_fma(p, t, 4.1666666666666664e-02);
  p = __builtin_fma(p, t, 1.6666666666666666e-01);
  p = __builtin_fma(p, t, 5.0e-01);
  p = __builtin_fma(p, t, 1.0);
  p = __builtin_fma(p, t, 1.0);
  return ldexp(p, (int)nf);
}

__device__ __forceinline__ double fast_div_d(double a, double b) {
  double r = __builtin_amdgcn_rcp(b);                       // ~2^-27
  r = __builtin_fma(__builtin_fma(-b, r, 1.0), r, r);       // NR -> ~2^-53
  r = __builtin_fma(__builtin_fma(-b, r, 1.0), r, r);       // NR -> ~0.5 ulp
  double q = a * r;
  q = __builtin_fma(__builtin_fma(-b, q, a), r, q);         // residual fixup
  return q;
}

__device__ __forceinline__ double tanh_att_d(double x) {
  const double ax = fmin(fabs(x), 22.0);      // tanh(22) == 1.0 in f64
  const double e  = exp_pos_d(2.0 * ax);
  const double r  = 1.0 - fast_div_d(2.0, e + 1.0);
  return copysign(r, x);
}

__device__ __forceinline__ double shfl_xor_d(double v, int m) {
  const long long l = __double_as_longlong(v);
  int lo = (int)(l & 0xffffffffll), hi = (int)(l >> 32);
  lo = __shfl_xor(lo, m, 64);
  hi = __shfl_xor(hi, m, 64);
  return __longlong_as_double(((long long)hi << 32) | (unsigned int)lo);
}

__device__ __forceinline__ double wave64_sum_d(double v) {
  #pragma unroll
  for (int m = 1; m < 64; m <<= 1) v += shfl_xor_d(v, m);
  return v;
}

struct SMem {
  double sredf[104];        // full f64 score sum per s (R13: one butterfly)
  unsigned char slist[104]; // compact list of unmasked s
  float  scores[104];
  float  evals[104];
  float  red_m, red_L;
  float  bc_lp;
  int    bc_sel;
};

extern "C" __global__ void ptrnet_prep(
    const float* __restrict__ eWih, const float* __restrict__ eWhh,
    const float* __restrict__ ebih, const float* __restrict__ ebhh,
    const float* __restrict__ dWih, const float* __restrict__ dWhh,
    const float* __restrict__ dbih, const float* __restrict__ dbhh,
    const float* __restrict__ We,  const float* __restrict__ Wd,
    char* __restrict__ wsb)
{
  const int idx = blockIdx.x * blockDim.x + threadIdx.x;
  const int stride = gridDim.x * blockDim.x;
  float* WHE = (float*)(wsb + B_WHE);
  float* WHD = (float*)(wsb + B_WHD);
  float* WET = (float*)(wsb + B_WET);
  float* WDT = (float*)(wsb + B_WDT);
  double* WXE = (double*)(wsb + B_WXE);
  double* WXD = (double*)(wsb + B_WXD);

  // Whh^T packs: [k][u][gate] (f32 verbatim -- exact)
  for (int i = idx; i < 256*256*4; i += stride) {
    const int g = i & 3, u = (i >> 2) & 255, k = i >> 10;
    WHE[i] = eWhh[(g*256 + u)*256 + k];
    WHD[i] = dWhh[(g*256 + u)*256 + k];
  }
  // We^T / Wd^T: [k][u]
  for (int i = idx; i < 256*256; i += stride) {
    const int u = i & 255, k = i >> 8;
    WET[i] = We[u*256 + k];
    WDT[i] = Wd[u*256 + k];
  }
  // Wih + bias pack (f64): [u][16] = {i0,i1,f0,f1,g0,g1,o0,o1, bi,bf,bg,bo}
  for (int i = idx; i < 256*16; i += stride) {
    const int f = i & 15, u = i >> 4;
    double ve = 0.0, vd = 0.0;
    if (f < 8) {
      const int gg = f >> 1, d = f & 1;
      ve = (double)eWih[(gg*256+u)*2 + d];
      vd = (double)dWih[(gg*256+u)*2 + d];
    } else if (f < 12) {
      const int gg = f - 8;
      ve = (double)ebih[gg*256+u] + (double)ebhh[gg*256+u];
      vd = (double)dbih[gg*256+u] + (double)dbhh[gg*256+u];
    }
    WXE[i] = ve;
    WXD[i] = vd;
  }
}

extern "C" __global__ void __launch_bounds__(256, 2)
ptrnet_main(char* __restrict__ wsb,
            const float* __restrict__ x,
            const float* __restrict__ be,
            const float* __restrict__ bd,
            const float* __restrict__ Vw,
            const float* __restrict__ Vb,
            const float* __restrict__ start,
            float* __restrict__ out)
{
  __shared__ double hls[2][256];   // block-private h state, ping-pong
  __shared__ double dls[256];      // dec_proj row (R13: shared for quad reads)
  __shared__ SMem sm;
  __shared__ float s_din[2];
  const int b   = blockIdx.x;      // one block per batch element
  const int tid = threadIdx.x;     // thread = hidden unit u
  const int lane = tid & 63;
  const int w = __builtin_amdgcn_readfirstlane(tid >> 6);

  const float* WHE = (const float*)(wsb + B_WHE);
  const float* WHD = (const float*)(wsb + B_WHD);
  const float* WET = (const float*)(wsb + B_WET);
  const float* WDT = (const float*)(wsb + B_WDT);
  const double* wxE = (const double*)(wsb + B_WXE) + tid*16;
  const double* wxD = (const double*)(wsb + B_WXD) + tid*16;
  double* ep = (double*)(wsb + B_EP) + (size_t)b*25600;   // block-private

  const double be_u = (double)be[tid];
  const double bd_u = (double)bd[tid];
  const double vb0  = (double)Vb[0];
  // R13: per-lane Vw quad (u = 4*lane + j), loop-invariant over all steps
  const double vq0 = (double)Vw[lane*4 + 0];
  const double vq1 = (double)Vw[lane*4 + 1];
  const double vq2 = (double)Vw[lane*4 + 2];
  const double vq3 = (double)Vw[lane*4 + 3];

  double c_state = 0.0;
  int par = 0;
  hls[0][tid] = 0.0;
  if (tid < 2) s_din[tid] = start[tid];
  __syncthreads();

  // ============================ encoder ============================
  for (int t = 0; t < 100; ++t) {
    const double x0 = (double)x[(b*100 + t)*2 + 0];
    const double x1 = (double)x[(b*100 + t)*2 + 1];
    double a0 = 0.0, a1 = 0.0, a2 = 0.0, a3 = 0.0, ae = 0.0;
    const double* hrow = hls[par];
    #pragma unroll 4
    for (int k = 0; k < 256; ++k) {
      const double hk = hrow[k];                       // LDS broadcast
      const float4 wf = *(const float4*)(WHE + k*1024 + tid*4);
      const float  we = WET[k*256 + tid];
      a0 = fma((double)wf.x, hk, a0);
      a1 = fma((double)wf.y, hk, a1);
      a2 = fma((double)wf.z, hk, a2);
      a3 = fma((double)wf.w, hk, a3);
      ae = fma((double)we,  hk, ae);
    }
    const double gi = a0 + fma(wxE[0], x0, fma(wxE[1], x1, wxE[8]));
    const double gf = a1 + fma(wxE[2], x0, fma(wxE[3], x1, wxE[9]));
    const double gg = a2 + fma(wxE[4], x0, fma(wxE[5], x1, wxE[10]));
    const double go = a3 + fma(wxE[6], x0, fma(wxE[7], x1, wxE[11]));
    const double cn = sigmoid_d(gf)*c_state + sigmoid_d(gi)*tanh(gg);
    const double hn = sigmoid_d(go)*tanh(cn);
    c_state = cn;
    if (t > 0) ep[(t-1)*256 + tid] = ae + be_u;   // ep[t-1] = We*h^(t)+be
    hls[par ^ 1][tid] = hn;
    __syncthreads();
    par ^= 1;
  }
  // ep[99] from h^(100)
  {
    double ae = 0.0;
    const double* hrow = hls[par];
    #pragma unroll 4
    for (int k = 0; k < 256; ++k)
      ae = fma((double)WET[k*256 + tid], hrow[k], ae);
    ep[99*256 + tid] = ae + be_u;
  }

  // ===================== decoder =====================
  unsigned long long m0 = 0ull, m1 = 0ull;
  float lp_acc = 0.0f;

  for (int t = 0; t < 100; ++t) {
    // ---------- LSTM cell ----------
    {
      const double x0 = (double)s_din[0];
      const double x1 = (double)s_din[1];
      double a0 = 0.0, a1 = 0.0, a2 = 0.0, a3 = 0.0;
      const double* hrow = hls[par];
      #pragma unroll 4
      for (int k = 0; k < 256; ++k) {
        const double hk = hrow[k];
        const float4 wf = *(const float4*)(WHD + k*1024 + tid*4);
        a0 = fma((double)wf.x, hk, a0);
        a1 = fma((double)wf.y, hk, a1);
        a2 = fma((double)wf.z, hk, a2);
        a3 = fma((double)wf.w, hk, a3);
      }
      const double gi = a0 + fma(wxD[0], x0, fma(wxD[1], x1, wxD[8]));
      const double gf = a1 + fma(wxD[2], x0, fma(wxD[3], x1, wxD[9]));
      const double gg = a2 + fma(wxD[4], x0, fma(wxD[5], x1, wxD[10]));
      const double go = a3 + fma(wxD[6], x0, fma(wxD[7], x1, wxD[11]));
      const double cn = sigmoid_d(gf)*c_state + sigmoid_d(gi)*tanh(gg);
      const double hn = sigmoid_d(go)*tanh(cn);
      c_state = cn;
      hls[par ^ 1][tid] = hn;
      __syncthreads();
      par ^= 1;
    }
    // ---------- dec_proj row -> LDS ----------
    {
      double ad = 0.0;
      const double* hrow = hls[par];
      #pragma unroll 4
      for (int k = 0; k < 256; ++k)
        ad = fma((double)WDT[k*256 + tid], hrow[k], ad);
      dls[tid] = ad + bd_u;
    }
    // ---------- compact unmasked-s list (branch-free popcount prefix) ----
    {
      const unsigned long long um0 = ~m0;
      const unsigned long long um1 = (~m1) & 0xFFFFFFFFFull;  // 36 bits
      if (tid < 100) {
        bool unm; int pre;
        if (tid < 64) {
          unm = ((um0 >> tid) & 1ull) != 0ull;
          pre = __popcll(um0 & ((1ull << tid) - 1ull));
        } else {
          const int r = tid - 64;
          unm = ((um1 >> r) & 1ull) != 0ull;
          pre = __popcll(um0) + __popcll(um1 & ((1ull << r) - 1ull));
        }
        if (unm) sm.slist[pre] = (unsigned char)tid;
      }
    }
    __syncthreads();
    // ---------- f64-exact scores, wave-distributed over unmasked s -------
    // wave w takes list entries w, w+4, ...; lane covers u = 4*lane..4*lane+3
    // -> one 64-lane butterfly = full 256-u sum (no cross-wave combine).
    {
      const int scnt = 100 - t;
      const double dpq0 = dls[lane*4 + 0];
      const double dpq1 = dls[lane*4 + 1];
      const double dpq2 = dls[lane*4 + 2];
      const double dpq3 = dls[lane*4 + 3];
      #pragma unroll 2
      for (int i = w; i < scnt; i += 4) {
        const int s = (int)sm.slist[i];
        const double* er = ep + s*256 + lane*4;
        const double2 e01 = *(const double2*)(er);
        const double2 e23 = *(const double2*)(er + 2);
        double p =        tanh_att_d(e01.x + dpq0) * vq0;
        p = __builtin_fma(tanh_att_d(e01.y + dpq1), vq1, p);
        p = __builtin_fma(tanh_att_d(e23.x + dpq2), vq2, p);
        p = __builtin_fma(tanh_att_d(e23.y + dpq3), vq3, p);
        p = wave64_sum_d(p);
        if (lane == 0) sm.sredf[s] = p;
      }
      __syncthreads();
      // ---------- np-faithful fp32 log_softmax selection (FROZEN) --------
      if (tid < 100) {
        const bool masked = (tid < 64) ? (((m0 >> tid) & 1ull) != 0ull)
                                       : (((m1 >> (tid-64)) & 1ull) != 0ull);
        // single rounding of the exact score to fp32 (reference dtype)
        sm.scores[tid] = masked ? -__builtin_inff()
                                : (float)(sm.sredf[tid] + vb0);
      }
      __syncthreads();
      if (w == 0) {   // m = max(scores), fp32
        const float v0 = sm.scores[lane];
        const float v1 = (lane < 36) ? sm.scores[64 + lane] : -__builtin_inff();
        float mv = fmaxf(v0, v1);
        #pragma unroll
        for (int mm = 1; mm < 64; mm <<= 1)
          mv = fmaxf(mv, __shfl_xor(mv, mm, 64));
        if (lane == 0) sm.red_m = mv;
      }
      __syncthreads();
      if (tid < 100)
        sm.evals[tid] = expf(__fsub_rn(sm.scores[tid], sm.red_m));
      __syncthreads();
      if (tid == 0) {
        // numpy pairwise_sum for n=100: 8 accumulators over 0..95,
        // combine ((r0+r1)+(r2+r3))+((r4+r5)+(r6+r7)), sequential tail 96..99
        float rr[8];
        #pragma unroll
        for (int j = 0; j < 8; ++j) rr[j] = sm.evals[j];
        for (int i = 8; i < 96; i += 8) {
          #pragma unroll
          for (int j = 0; j < 8; ++j) rr[j] = __fadd_rn(rr[j], sm.evals[i + j]);
        }
        float res = __fadd_rn(
            __fadd_rn(__fadd_rn(rr[0], rr[1]), __fadd_rn(rr[2], rr[3])),
            __fadd_rn(__fadd_rn(rr[4], rr[5]), __fadd_rn(rr[6], rr[7])));
        res = __fadd_rn(res, sm.evals[96]);
        res = __fadd_rn(res, sm.evals[97]);
        res = __fadd_rn(res, sm.evals[98]);
        res = __fadd_rn(res, sm.evals[99]);
        sm.red_L = logf(res);
      }
      __syncthreads();
      if (w == 0) {   // lp = fl(fl(s - m) - L); argmax(lp), first index on ties
        const float m = sm.red_m, L = sm.red_L;
        const float lp0 = __fsub_rn(__fsub_rn(sm.scores[lane], m), L);
        const float lp1 = (lane < 36)
            ? __fsub_rn(__fsub_rn(sm.scores[64 + lane], m), L)
            : -__builtin_inff();
        float bv; int bi;
        if (lp0 >= lp1) { bv = lp0; bi = lane; } else { bv = lp1; bi = 64 + lane; }
        #pragma unroll
        for (int mm = 1; mm < 64; mm <<= 1) {
          const float ov = __shfl_xor(bv, mm, 64);
          const int   oi = __shfl_xor(bi, mm, 64);
          if (ov > bv || (ov == bv && oi < bi)) { bv = ov; bi = oi; }
        }
        if (lane == 0) { sm.bc_sel = bi; sm.bc_lp = bv; }
      }
      __syncthreads();
      const int sel = __builtin_amdgcn_readfirstlane(sm.bc_sel);
      lp_acc = __fadd_rn(lp_acc, sm.bc_lp);   // np axis-0 sum: sequential fp32
      if (sel < 64) m0 |= (1ull << sel); else m1 |= (1ull << (sel - 64));
      if (tid == 0) out[b*100 + t] = (float)sel;
      if (tid < 2) s_din[tid] = x[(b*100 + sel)*2 + tid];
      __syncthreads();
    }
  }

  // ---------------- outputs ----------------
  if (tid == 0) out[51200 + b] = lp_acc;
  out[51712 + b*256 + tid] = (float)hls[par][tid];
}

extern "C" void kernel_launch(void* const* d_in, const int* in_sizes, int n_in,
                              void* d_out, int out_size, void* d_ws, size_t ws_size,
                              hipStream_t stream) {
  const float* x     = (const float*)d_in[0];
  const float* eWih  = (const float*)d_in[1];
  const float* eWhh  = (const float*)d_in[2];
  const float* ebih  = (const float*)d_in[3];
  const float* ebhh  = (const float*)d_in[4];
  const float* dWih  = (const float*)d_in[5];
  const float* dWhh  = (const float*)d_in[6];
  const float* dbih  = (const float*)d_in[7];
  const float* dbhh  = (const float*)d_in[8];
  const float* We    = (const float*)d_in[9];
  const float* be    = (const float*)d_in[10];
  const float* Wd    = (const float*)d_in[11];
  const float* bd    = (const float*)d_in[12];
  const float* vw    = (const float*)d_in[13];
  const float* vb    = (const float*)d_in[14];
  const float* start = (const float*)d_in[15];
  char* ws    = (char*)d_ws;
  float* outp = (float*)d_out;

  ptrnet_prep<<<dim3(512), dim3(256), 0, stream>>>(
      eWih, eWhh, ebih, ebhh, dWih, dWhh, dbih, dbhh, We, Wd, ws);

  ptrnet_main<<<dim3(512), dim3(256), 0, stream>>>(ws, x, be, bd, vw, vb,
                                                   start, outp);
}

// Round 2
// 7592.258 us; speedup vs baseline: 1.4984x; 1.0403x over previous
//
#include <hip/hip_runtime.h>

// Pointer network: encoder LSTM -> enc_proj -> decoder LSTM + attention argmax.
// B=512, S=100, D=2, H=256.
//
// NUMERICS (FROZEN since R7, absmax 7.0 <= 7.2): f64 state trajectory (h/c/
// gates/ep/dp in f64; chain ORDER may vary -- error ~1e-13 << decision gaps)
// + EXACT np-faithful fp32 log_softmax selection (single f32 rounding of
// scores, pairwise-8 sum of exps, lp=fl(fl(s-m)-L), argmax(lp) first-index,
// lp_acc sequential fp32). Selection block below is byte-identical to R7-R13.
//
// R12: barrier-free, one block per batch element (thread = hidden unit).
// R13: 8->1 butterfly score restructure + branch-free f64 tanh (score path).
// R14: k-SPLIT occupancy doubling. 512 threads/block: thread (u=tid&255,
//  half=tid>>8) accumulates matvec partials over 128 ks; upper half deposits
//  partials in LDS, lower half combines + gates. 16 waves/CU (4/SIMD) vs 8,
//  halves the per-thread FMA chain, score loop spreads over 8 waves. Only
//  f64 summation ORDER changes ((lo+hi) vs sequential) -- blessed class.

#define B_WHE  0ull                       // f32 [256 k][256 u][4 g] enc Whh^T
#define B_WHD  (B_WHE + 1048576ull)       // f32 dec
#define B_WET  (B_WHD + 1048576ull)       // f32 [256 k][256 u] We^T
#define B_WDT  (B_WET + 262144ull)        // Wd^T
#define B_WXE  (B_WDT + 262144ull)        // f64 [256 u][16] Wih+bias pack
#define B_WXD  (B_WXE + 32768ull)
#define B_EP   (B_WXD + 32768ull)         // f64 [512 b][100 t][256 u] = 104.9MB

__device__ __forceinline__ double sigmoid_d(double x) {
  return 1.0 / (1.0 + exp(-x));
}

// ---------- R13 branch-free f64 tanh (attention scores only) ----------
__device__ __forceinline__ double exp_pos_d(double a) {  // a in [0, 45]
  const double L2E    = 1.4426950408889634074;
  const double LN2_HI = 6.9314718036912381649e-01;   // ln2 hi (20 low bits 0)
  const double LN2_LO = 1.9082149292705877000e-10;
  const double nf = rint(a * L2E);
  double t = __builtin_fma(-nf, LN2_HI, a);
  t = __builtin_fma(-nf, LN2_LO, t);
  double p = 2.0876756987868099e-09;                 // 1/12!
  p = __builtin_fma(p, t, 2.5052108385441720e-08);   // 1/11!
  p = __builtin_fma(p, t, 2.7557319223985888e-07);
  p = __builtin_fma(p, t, 2.7557319223985893e-06);
  p = __builtin_fma(p, t, 2.4801587301587302e-05);
  p = __builtin_fma(p, t, 1.9841269841269841e-04);
  p = __builtin_fma(p, t, 1.3888888888888889e-03);
  p = __builtin_fma(p, t, 8.3333333333333332e-03);
  p = __builtin_fma(p, t, 4.1666666666666664e-02);
  p = __builtin_fma(p, t, 1.6666666666666666e-01);
  p = __builtin_fma(p, t, 5.0e-01);
  p = __builtin_fma(p, t, 1.0);
  p = __builtin_fma(p, t, 1.0);
  return ldexp(p, (int)nf);
}

__device__ __forceinline__ double fast_div_d(double a, double b) {
  double r = __builtin_amdgcn_rcp(b);                       // ~2^-27
  r = __builtin_fma(__builtin_fma(-b, r, 1.0), r, r);       // NR -> ~2^-53
  r = __builtin_fma(__builtin_fma(-b, r, 1.0), r, r);       // NR -> ~0.5 ulp
  double q = a * r;
  q = __builtin_fma(__builtin_fma(-b, q, a), r, q);         // residual fixup
  return q;
}

__device__ __forceinline__ double tanh_att_d(double x) {
  const double ax = fmin(fabs(x), 22.0);      // tanh(22) == 1.0 in f64
  const double e  = exp_pos_d(2.0 * ax);
  const double r  = 1.0 - fast_div_d(2.0, e + 1.0);
  return copysign(r, x);
}

__device__ __forceinline__ double shfl_xor_d(double v, int m) {
  const long long l = __double_as_longlong(v);
  int lo = (int)(l & 0xffffffffll), hi = (int)(l >> 32);
  lo = __shfl_xor(lo, m, 64);
  hi = __shfl_xor(hi, m, 64);
  return __longlong_as_double(((long long)hi << 32) | (unsigned int)lo);
}

__device__ __forceinline__ double wave64_sum_d(double v) {
  #pragma unroll
  for (int m = 1; m < 64; m <<= 1) v += shfl_xor_d(v, m);
  return v;
}

struct SMem {
  double sredf[104];        // full f64 score sum per s (one butterfly)
  unsigned char slist[104]; // compact list of unmasked s
  float  scores[104];
  float  evals[104];
  float  red_m, red_L;
  float  bc_lp;
  int    bc_sel;
};

extern "C" __global__ void ptrnet_prep(
    const float* __restrict__ eWih, const float* __restrict__ eWhh,
    const float* __restrict__ ebih, const float* __restrict__ ebhh,
    const float* __restrict__ dWih, const float* __restrict__ dWhh,
    const float* __restrict__ dbih, const float* __restrict__ dbhh,
    const float* __restrict__ We,  const float* __restrict__ Wd,
    char* __restrict__ wsb)
{
  const int idx = blockIdx.x * blockDim.x + threadIdx.x;
  const int stride = gridDim.x * blockDim.x;
  float* WHE = (float*)(wsb + B_WHE);
  float* WHD = (float*)(wsb + B_WHD);
  float* WET = (float*)(wsb + B_WET);
  float* WDT = (float*)(wsb + B_WDT);
  double* WXE = (double*)(wsb + B_WXE);
  double* WXD = (double*)(wsb + B_WXD);

  // Whh^T packs: [k][u][gate] (f32 verbatim -- exact)
  for (int i = idx; i < 256*256*4; i += stride) {
    const int g = i & 3, u = (i >> 2) & 255, k = i >> 10;
    WHE[i] = eWhh[(g*256 + u)*256 + k];
    WHD[i] = dWhh[(g*256 + u)*256 + k];
  }
  // We^T / Wd^T: [k][u]
  for (int i = idx; i < 256*256; i += stride) {
    const int u = i & 255, k = i >> 8;
    WET[i] = We[u*256 + k];
    WDT[i] = Wd[u*256 + k];
  }
  // Wih + bias pack (f64): [u][16] = {i0,i1,f0,f1,g0,g1,o0,o1, bi,bf,bg,bo}
  for (int i = idx; i < 256*16; i += stride) {
    const int f = i & 15, u = i >> 4;
    double ve = 0.0, vd = 0.0;
    if (f < 8) {
      const int gg = f >> 1, d = f & 1;
      ve = (double)eWih[(gg*256+u)*2 + d];
      vd = (double)dWih[(gg*256+u)*2 + d];
    } else if (f < 12) {
      const int gg = f - 8;
      ve = (double)ebih[gg*256+u] + (double)ebhh[gg*256+u];
      vd = (double)dbih[gg*256+u] + (double)dbhh[gg*256+u];
    }
    WXE[i] = ve;
    WXD[i] = vd;
  }
}

extern "C" __global__ void __launch_bounds__(512, 4)
ptrnet_main(char* __restrict__ wsb,
            const float* __restrict__ x,
            const float* __restrict__ be,
            const float* __restrict__ bd,
            const float* __restrict__ Vw,
            const float* __restrict__ Vb,
            const float* __restrict__ start,
            float* __restrict__ out)
{
  __shared__ double hls[2][256];   // block-private h state, ping-pong
  __shared__ double dls[256];      // dec_proj row
  __shared__ double pred[256][5];  // R14: upper-half matvec partials
  __shared__ SMem sm;
  __shared__ float s_din[2];
  const int b    = blockIdx.x;     // one block per batch element
  const int tid  = threadIdx.x;
  const int u    = tid & 255;      // hidden unit
  const int half = tid >> 8;       // k-split half: k in [half*128, half*128+128)
  const int k0   = half << 7;
  const int lane = tid & 63;
  const int w = __builtin_amdgcn_readfirstlane(tid >> 6);   // 0..7

  const float* WHE = (const float*)(wsb + B_WHE);
  const float* WHD = (const float*)(wsb + B_WHD);
  const float* WET = (const float*)(wsb + B_WET);
  const float* WDT = (const float*)(wsb + B_WDT);
  const double* wxE = (const double*)(wsb + B_WXE) + u*16;
  const double* wxD = (const double*)(wsb + B_WXD) + u*16;
  double* ep = (double*)(wsb + B_EP) + (size_t)b*25600;   // block-private

  const double be_u = (double)be[u];
  const double bd_u = (double)bd[u];
  const double vb0  = (double)Vb[0];
  // per-lane Vw quad (u' = 4*lane + j), loop-invariant over all steps
  const double vq0 = (double)Vw[lane*4 + 0];
  const double vq1 = (double)Vw[lane*4 + 1];
  const double vq2 = (double)Vw[lane*4 + 2];
  const double vq3 = (double)Vw[lane*4 + 3];

  double c_state = 0.0;            // live on half==0 threads
  int par = 0;
  if (tid < 256) hls[0][tid] = 0.0;
  if (tid < 2) s_din[tid] = start[tid];
  __syncthreads();

  // ============================ encoder ============================
  for (int t = 0; t < 100; ++t) {
    const double x0 = (double)x[(b*100 + t)*2 + 0];
    const double x1 = (double)x[(b*100 + t)*2 + 1];
    double a0 = 0.0, a1 = 0.0, a2 = 0.0, a3 = 0.0, ae = 0.0;
    const double* hrow = hls[par];
    #pragma unroll 4
    for (int k = k0; k < k0 + 128; ++k) {
      const double hk = hrow[k];                       // LDS broadcast
      const float4 wf = *(const float4*)(WHE + k*1024 + u*4);
      const float  we = WET[k*256 + u];
      a0 = fma((double)wf.x, hk, a0);
      a1 = fma((double)wf.y, hk, a1);
      a2 = fma((double)wf.z, hk, a2);
      a3 = fma((double)wf.w, hk, a3);
      ae = fma((double)we,  hk, ae);
    }
    if (half == 1) {
      pred[u][0] = a0; pred[u][1] = a1; pred[u][2] = a2;
      pred[u][3] = a3; pred[u][4] = ae;
    }
    __syncthreads();
    if (half == 0) {
      a0 += pred[u][0]; a1 += pred[u][1]; a2 += pred[u][2];
      a3 += pred[u][3]; ae += pred[u][4];
      const double gi = a0 + fma(wxE[0], x0, fma(wxE[1], x1, wxE[8]));
      const double gf = a1 + fma(wxE[2], x0, fma(wxE[3], x1, wxE[9]));
      const double gg = a2 + fma(wxE[4], x0, fma(wxE[5], x1, wxE[10]));
      const double go = a3 + fma(wxE[6], x0, fma(wxE[7], x1, wxE[11]));
      const double cn = sigmoid_d(gf)*c_state + sigmoid_d(gi)*tanh(gg);
      const double hn = sigmoid_d(go)*tanh(cn);
      c_state = cn;
      if (t > 0) ep[(t-1)*256 + u] = ae + be_u;   // ep[t-1] = We*h^(t)+be
      hls[par ^ 1][u] = hn;
    }
    __syncthreads();
    par ^= 1;
  }
  // ep[99] from h^(100)
  {
    double ae = 0.0;
    const double* hrow = hls[par];
    #pragma unroll 4
    for (int k = k0; k < k0 + 128; ++k)
      ae = fma((double)WET[k*256 + u], hrow[k], ae);
    if (half == 1) pred[u][0] = ae;
    __syncthreads();
    if (half == 0) ep[99*256 + u] = ae + pred[u][0] + be_u;
  }

  // ===================== decoder =====================
  unsigned long long m0 = 0ull, m1 = 0ull;
  float lp_acc = 0.0f;

  for (int t = 0; t < 100; ++t) {
    // ---------- LSTM cell (k-split) ----------
    {
      const double x0 = (double)s_din[0];
      const double x1 = (double)s_din[1];
      double a0 = 0.0, a1 = 0.0, a2 = 0.0, a3 = 0.0;
      const double* hrow = hls[par];
      #pragma unroll 4
      for (int k = k0; k < k0 + 128; ++k) {
        const double hk = hrow[k];
        const float4 wf = *(const float4*)(WHD + k*1024 + u*4);
        a0 = fma((double)wf.x, hk, a0);
        a1 = fma((double)wf.y, hk, a1);
        a2 = fma((double)wf.z, hk, a2);
        a3 = fma((double)wf.w, hk, a3);
      }
      if (half == 1) {
        pred[u][0] = a0; pred[u][1] = a1; pred[u][2] = a2; pred[u][3] = a3;
      }
      __syncthreads();
      if (half == 0) {
        a0 += pred[u][0]; a1 += pred[u][1];
        a2 += pred[u][2]; a3 += pred[u][3];
        const double gi = a0 + fma(wxD[0], x0, fma(wxD[1], x1, wxD[8]));
        const double gf = a1 + fma(wxD[2], x0, fma(wxD[3], x1, wxD[9]));
        const double gg = a2 + fma(wxD[4], x0, fma(wxD[5], x1, wxD[10]));
        const double go = a3 + fma(wxD[6], x0, fma(wxD[7], x1, wxD[11]));
        const double cn = sigmoid_d(gf)*c_state + sigmoid_d(gi)*tanh(gg);
        const double hn = sigmoid_d(go)*tanh(cn);
        c_state = cn;
        hls[par ^ 1][u] = hn;
      }
      __syncthreads();
      par ^= 1;
    }
    // ---------- dec_proj row (k-split) -> LDS ----------
    {
      double ad = 0.0;
      const double* hrow = hls[par];
      #pragma unroll 4
      for (int k = k0; k < k0 + 128; ++k)
        ad = fma((double)WDT[k*256 + u], hrow[k], ad);
      if (half == 1) pred[u][0] = ad;
      // compact unmasked-s list (branch-free popcount prefix) -- register-only
      {
        const unsigned long long um0 = ~m0;
        const unsigned long long um1 = (~m1) & 0xFFFFFFFFFull;  // 36 bits
        if (tid < 100) {
          bool unm; int pre;
          if (tid < 64) {
            unm = ((um0 >> tid) & 1ull) != 0ull;
            pre = __popcll(um0 & ((1ull << tid) - 1ull));
          } else {
            const int r = tid - 64;
            unm = ((um1 >> r) & 1ull) != 0ull;
            pre = __popcll(um0) + __popcll(um1 & ((1ull << r) - 1ull));
          }
          if (unm) sm.slist[pre] = (unsigned char)tid;
        }
      }
      __syncthreads();
      if (half == 0) dls[u] = ad + pred[u][0] + bd_u;
    }
    __syncthreads();
    // ---------- f64-exact scores, distributed over 8 waves ----------
    // wave w takes list entries w, w+8, ...; lane covers u' = 4*lane..4*lane+3
    // -> one 64-lane butterfly = full 256-u sum (no cross-wave combine).
    {
      const int scnt = 100 - t;
      const double dpq0 = dls[lane*4 + 0];
      const double dpq1 = dls[lane*4 + 1];
      const double dpq2 = dls[lane*4 + 2];
      const double dpq3 = dls[lane*4 + 3];
      #pragma unroll 2
      for (int i = w; i < scnt; i += 8) {
        const int s = (int)sm.slist[i];
        const double* er = ep + s*256 + lane*4;
        const double2 e01 = *(const double2*)(er);
        const double2 e23 = *(const double2*)(er + 2);
        double p =        tanh_att_d(e01.x + dpq0) * vq0;
        p = __builtin_fma(tanh_att_d(e01.y + dpq1), vq1, p);
        p = __builtin_fma(tanh_att_d(e23.x + dpq2), vq2, p);
        p = __builtin_fma(tanh_att_d(e23.y + dpq3), vq3, p);
        p = wave64_sum_d(p);
        if (lane == 0) sm.sredf[s] = p;
      }
      __syncthreads();
      // ---------- np-faithful fp32 log_softmax selection (FROZEN) --------
      if (tid < 100) {
        const bool masked = (tid < 64) ? (((m0 >> tid) & 1ull) != 0ull)
                                       : (((m1 >> (tid-64)) & 1ull) != 0ull);
        // single rounding of the exact score to fp32 (reference dtype)
        sm.scores[tid] = masked ? -__builtin_inff()
                                : (float)(sm.sredf[tid] + vb0);
      }
      __syncthreads();
      if (w == 0) {   // m = max(scores), fp32
        const float v0 = sm.scores[lane];
        const float v1 = (lane < 36) ? sm.scores[64 + lane] : -__builtin_inff();
        float mv = fmaxf(v0, v1);
        #pragma unroll
        for (int mm = 1; mm < 64; mm <<= 1)
          mv = fmaxf(mv, __shfl_xor(mv, mm, 64));
        if (lane == 0) sm.red_m = mv;
      }
      __syncthreads();
      if (tid < 100)
        sm.evals[tid] = expf(__fsub_rn(sm.scores[tid], sm.red_m));
      __syncthreads();
      if (tid == 0) {
        // numpy pairwise_sum for n=100: 8 accumulators over 0..95,
        // combine ((r0+r1)+(r2+r3))+((r4+r5)+(r6+r7)), sequential tail 96..99
        float rr[8];
        #pragma unroll
        for (int j = 0; j < 8; ++j) rr[j] = sm.evals[j];
        for (int i = 8; i < 96; i += 8) {
          #pragma unroll
          for (int j = 0; j < 8; ++j) rr[j] = __fadd_rn(rr[j], sm.evals[i + j]);
        }
        float res = __fadd_rn(
            __fadd_rn(__fadd_rn(rr[0], rr[1]), __fadd_rn(rr[2], rr[3])),
            __fadd_rn(__fadd_rn(rr[4], rr[5]), __fadd_rn(rr[6], rr[7])));
        res = __fadd_rn(res, sm.evals[96]);
        res = __fadd_rn(res, sm.evals[97]);
        res = __fadd_rn(res, sm.evals[98]);
        res = __fadd_rn(res, sm.evals[99]);
        sm.red_L = logf(res);
      }
      __syncthreads();
      if (w == 0) {   // lp = fl(fl(s - m) - L); argmax(lp), first index on ties
        const float m = sm.red_m, L = sm.red_L;
        const float lp0 = __fsub_rn(__fsub_rn(sm.scores[lane], m), L);
        const float lp1 = (lane < 36)
            ? __fsub_rn(__fsub_rn(sm.scores[64 + lane], m), L)
            : -__builtin_inff();
        float bv; int bi;
        if (lp0 >= lp1) { bv = lp0; bi = lane; } else { bv = lp1; bi = 64 + lane; }
        #pragma unroll
        for (int mm = 1; mm < 64; mm <<= 1) {
          const float ov = __shfl_xor(bv, mm, 64);
          const int   oi = __shfl_xor(bi, mm, 64);
          if (ov > bv || (ov == bv && oi < bi)) { bv = ov; bi = oi; }
        }
        if (lane == 0) { sm.bc_sel = bi; sm.bc_lp = bv; }
      }
      __syncthreads();
      const int sel = __builtin_amdgcn_readfirstlane(sm.bc_sel);
      lp_acc = __fadd_rn(lp_acc, sm.bc_lp);   // np axis-0 sum: sequential fp32
      if (sel < 64) m0 |= (1ull << sel); else m1 |= (1ull << (sel - 64));
      if (tid == 0) out[b*100 + t] = (float)sel;
      if (tid < 2) s_din[tid] = x[(b*100 + sel)*2 + tid];
      __syncthreads();
    }
  }

  // ---------------- outputs ----------------
  if (tid == 0) out[51200 + b] = lp_acc;
  if (tid < 256) out[51712 + b*256 + tid] = (float)hls[par][tid];
}

extern "C" void kernel_launch(void* const* d_in, const int* in_sizes, int n_in,
                              void* d_out, int out_size, void* d_ws, size_t ws_size,
                              hipStream_t stream) {
  const float* x     = (const float*)d_in[0];
  const float* eWih  = (const float*)d_in[1];
  const float* eWhh  = (const float*)d_in[2];
  const float* ebih  = (const float*)d_in[3];
  const float* ebhh  = (const float*)d_in[4];
  const float* dWih  = (const float*)d_in[5];
  const float* dWhh  = (const float*)d_in[6];
  const float* dbih  = (const float*)d_in[7];
  const float* dbhh  = (const float*)d_in[8];
  const float* We    = (const float*)d_in[9];
  const float* be    = (const float*)d_in[10];
  const float* Wd    = (const float*)d_in[11];
  const float* bd    = (const float*)d_in[12];
  const float* vw    = (const float*)d_in[13];
  const float* vb    = (const float*)d_in[14];
  const float* start = (const float*)d_in[15];
  char* ws    = (char*)d_ws;
  float* outp = (float*)d_out;

  ptrnet_prep<<<dim3(512), dim3(256), 0, stream>>>(
      eWih, eWhh, ebih, ebhh, dWih, dWhh, dbih, dbhh, We, Wd, ws);

  ptrnet_main<<<dim3(512), dim3(512), 0, stream>>>(ws, x, be, bd, vw, vb,
                                                   start, outp);
}

// Round 3
// 7318.599 us; speedup vs baseline: 1.5544x; 1.0374x over previous
//
#include <hip/hip_runtime.h>

// Pointer network: encoder LSTM -> enc_proj -> decoder LSTM + attention argmax.
// B=512, S=100, D=2, H=256.
//
// NUMERICS (FROZEN since R7, absmax 7.0 <= 7.2): f64 state trajectory (h/c/
// gates/ep/dp in f64; chain ORDER may vary -- error ~1e-13 << decision gaps)
// + EXACT np-faithful fp32 log_softmax selection (single f32 rounding of
// scores, pairwise-8 sum of exps, lp=fl(fl(s-m)-L), argmax(lp) first-index,
// lp_acc sequential fp32). Selection block below is byte-identical to R7-R14.
//
// R12: barrier-free, one block per batch element (thread = hidden unit).
// R13: 8->1 butterfly score restructure + branch-free f64 tanh (score path).
// R14: k-split 512-thread blocks (half=tid>>8 covers 128 ks; LDS partials).
// R15: BATCH-PAIR blocks. Evidence: R14 doubled occupancy for +3% -> stall is
//  the shared per-step L2 weight re-stream (2.5 MB/CU/step ~= 3.7 ms of the
//  8.4 ms). One block now serves batches (b0,b1): each weight element is
//  loaded ONCE and FMA'd against both batches' h (10 FMA : 5 loads).
//  half0 finalizes/owns b0, half1 owns b1 (gates, c, ep, masks, selection) --
//  symmetric, no idle threads; selection runs per-batch in disjoint wave
//  groups. L2 weight traffic and cvt work halve. b1's partial combine is
//  high+low vs low+high -- IEEE-commutative, bit-identical to R14.

#define B_WHE  0ull                       // f32 [256 k][256 u][4 g] enc Whh^T
#define B_WHD  (B_WHE + 1048576ull)       // f32 dec
#define B_WET  (B_WHD + 1048576ull)       // f32 [256 k][256 u] We^T
#define B_WDT  (B_WET + 262144ull)        // Wd^T
#define B_WXE  (B_WDT + 262144ull)        // f64 [256 u][16] Wih+bias pack
#define B_WXD  (B_WXE + 32768ull)
#define B_EP   (B_WXD + 32768ull)         // f64 [512 b][100 t][256 u] = 104.9MB

__device__ __forceinline__ double sigmoid_d(double x) {
  return 1.0 / (1.0 + exp(-x));
}

// ---------- R13 branch-free f64 tanh (attention scores only) ----------
__device__ __forceinline__ double exp_pos_d(double a) {  // a in [0, 45]
  const double L2E    = 1.4426950408889634074;
  const double LN2_HI = 6.9314718036912381649e-01;   // ln2 hi (20 low bits 0)
  const double LN2_LO = 1.9082149292705877000e-10;
  const double nf = rint(a * L2E);
  double t = __builtin_fma(-nf, LN2_HI, a);
  t = __builtin_fma(-nf, LN2_LO, t);
  double p = 2.0876756987868099e-09;                 // 1/12!
  p = __builtin_fma(p, t, 2.5052108385441720e-08);   // 1/11!
  p = __builtin_fma(p, t, 2.7557319223985888e-07);
  p = __builtin_fma(p, t, 2.7557319223985893e-06);
  p = __builtin_fma(p, t, 2.4801587301587302e-05);
  p = __builtin_fma(p, t, 1.9841269841269841e-04);
  p = __builtin_fma(p, t, 1.3888888888888889e-03);
  p = __builtin_fma(p, t, 8.3333333333333332e-03);
  p = __builtin_fma(p, t, 4.1666666666666664e-02);
  p = __builtin_fma(p, t, 1.6666666666666666e-01);
  p = __builtin_fma(p, t, 5.0e-01);
  p = __builtin_fma(p, t, 1.0);
  p = __builtin_fma(p, t, 1.0);
  return ldexp(p, (int)nf);
}

__device__ __forceinline__ double fast_div_d(double a, double b) {
  double r = __builtin_amdgcn_rcp(b);                       // ~2^-27
  r = __builtin_fma(__builtin_fma(-b, r, 1.0), r, r);       // NR -> ~2^-53
  r = __builtin_fma(__builtin_fma(-b, r, 1.0), r, r);       // NR -> ~0.5 ulp
  double q = a * r;
  q = __builtin_fma(__builtin_fma(-b, q, a), r, q);         // residual fixup
  return q;
}

__device__ __forceinline__ double tanh_att_d(double x) {
  const double ax = fmin(fabs(x), 22.0);      // tanh(22) == 1.0 in f64
  const double e  = exp_pos_d(2.0 * ax);
  const double r  = 1.0 - fast_div_d(2.0, e + 1.0);
  return copysign(r, x);
}

__device__ __forceinline__ double shfl_xor_d(double v, int m) {
  const long long l = __double_as_longlong(v);
  int lo = (int)(l & 0xffffffffll), hi = (int)(l >> 32);
  lo = __shfl_xor(lo, m, 64);
  hi = __shfl_xor(hi, m, 64);
  return __longlong_as_double(((long long)hi << 32) | (unsigned int)lo);
}

__device__ __forceinline__ double wave64_sum_d(double v) {
  #pragma unroll
  for (int m = 1; m < 64; m <<= 1) v += shfl_xor_d(v, m);
  return v;
}

struct SMem {
  double sredf[104];        // full f64 score sum per s (one butterfly)
  unsigned char slist[104]; // compact list of unmasked s
  float  scores[104];
  float  evals[104];
  float  red_m, red_L;
  float  bc_lp;
  int    bc_sel;
};

extern "C" __global__ void ptrnet_prep(
    const float* __restrict__ eWih, const float* __restrict__ eWhh,
    const float* __restrict__ ebih, const float* __restrict__ ebhh,
    const float* __restrict__ dWih, const float* __restrict__ dWhh,
    const float* __restrict__ dbih, const float* __restrict__ dbhh,
    const float* __restrict__ We,  const float* __restrict__ Wd,
    char* __restrict__ wsb)
{
  const int idx = blockIdx.x * blockDim.x + threadIdx.x;
  const int stride = gridDim.x * blockDim.x;
  float* WHE = (float*)(wsb + B_WHE);
  float* WHD = (float*)(wsb + B_WHD);
  float* WET = (float*)(wsb + B_WET);
  float* WDT = (float*)(wsb + B_WDT);
  double* WXE = (double*)(wsb + B_WXE);
  double* WXD = (double*)(wsb + B_WXD);

  // Whh^T packs: [k][u][gate] (f32 verbatim -- exact)
  for (int i = idx; i < 256*256*4; i += stride) {
    const int g = i & 3, u = (i >> 2) & 255, k = i >> 10;
    WHE[i] = eWhh[(g*256 + u)*256 + k];
    WHD[i] = dWhh[(g*256 + u)*256 + k];
  }
  // We^T / Wd^T: [k][u]
  for (int i = idx; i < 256*256; i += stride) {
    const int u = i & 255, k = i >> 8;
    WET[i] = We[u*256 + k];
    WDT[i] = Wd[u*256 + k];
  }
  // Wih + bias pack (f64): [u][16] = {i0,i1,f0,f1,g0,g1,o0,o1, bi,bf,bg,bo}
  for (int i = idx; i < 256*16; i += stride) {
    const int f = i & 15, u = i >> 4;
    double ve = 0.0, vd = 0.0;
    if (f < 8) {
      const int gg = f >> 1, d = f & 1;
      ve = (double)eWih[(gg*256+u)*2 + d];
      vd = (double)dWih[(gg*256+u)*2 + d];
    } else if (f < 12) {
      const int gg = f - 8;
      ve = (double)ebih[gg*256+u] + (double)ebhh[gg*256+u];
      vd = (double)dbih[gg*256+u] + (double)dbhh[gg*256+u];
    }
    WXE[i] = ve;
    WXD[i] = vd;
  }
}

extern "C" __global__ void __launch_bounds__(512, 2)
ptrnet_main(char* __restrict__ wsb,
            const float* __restrict__ x,
            const float* __restrict__ be,
            const float* __restrict__ bd,
            const float* __restrict__ Vw,
            const float* __restrict__ Vb,
            const float* __restrict__ start,
            float* __restrict__ out)
{
  __shared__ double hls[2][2][256];   // [parity][batch][u] h state
  __shared__ double dls[2][256];      // [batch][u] dec_proj row
  __shared__ double pred[2][256][5];  // [batch][u][stream] cross-half partials
  __shared__ SMem sm[2];              // per-batch selection state
  __shared__ float s_din[2][2];       // [batch][d]
  const int b0   = blockIdx.x * 2;    // this block serves batches b0, b1
  const int b1   = b0 + 1;
  const int tid  = threadIdx.x;
  const int u    = tid & 255;         // hidden unit
  const int half = tid >> 8;          // k-split half AND owned batch
  const int k0   = half << 7;         // own k range [k0, k0+128)
  const int lane = tid & 63;
  const int w = __builtin_amdgcn_readfirstlane(tid >> 6);   // 0..7

  const float* WHE = (const float*)(wsb + B_WHE);
  const float* WHD = (const float*)(wsb + B_WHD);
  const float* WET = (const float*)(wsb + B_WET);
  const float* WDT = (const float*)(wsb + B_WDT);
  const double* wxE = (const double*)(wsb + B_WXE) + u*16;
  const double* wxD = (const double*)(wsb + B_WXD) + u*16;
  double* ep0 = (double*)(wsb + B_EP) + (size_t)b0*25600;
  double* ep1 = (double*)(wsb + B_EP) + (size_t)b1*25600;
  double* epown = half ? ep1 : ep0;   // the ep this thread's owned batch writes
  const int bown = half ? b1 : b0;    // owned batch global index

  const double be_u = (double)be[u];
  const double bd_u = (double)bd[u];
  const double vb0  = (double)Vb[0];
  // per-lane Vw quad (u' = 4*lane + j), loop-invariant over all steps
  const double vq0 = (double)Vw[lane*4 + 0];
  const double vq1 = (double)Vw[lane*4 + 1];
  const double vq2 = (double)Vw[lane*4 + 2];
  const double vq3 = (double)Vw[lane*4 + 3];

  double c_state = 0.0;               // owned batch's c for unit u
  int par = 0;
  if (tid < 256) { hls[0][0][tid] = 0.0; hls[0][1][tid] = 0.0; }
  if (tid < 2) { s_din[0][tid] = start[tid]; s_din[1][tid] = start[tid]; }
  __syncthreads();

  // ============================ encoder ============================
  for (int t = 0; t < 100; ++t) {
    const double x00 = (double)x[(b0*100 + t)*2 + 0];
    const double x01 = (double)x[(b0*100 + t)*2 + 1];
    const double x10 = (double)x[(b1*100 + t)*2 + 0];
    const double x11 = (double)x[(b1*100 + t)*2 + 1];
    double p0 = 0.0, p1 = 0.0, p2 = 0.0, p3 = 0.0, p4 = 0.0;  // b0 partials
    double q0 = 0.0, q1 = 0.0, q2 = 0.0, q3 = 0.0, q4 = 0.0;  // b1 partials
    const double* h0 = hls[par][0];
    const double* h1 = hls[par][1];
    #pragma unroll 4
    for (int k = k0; k < k0 + 128; ++k) {
      const double hk0 = h0[k];                      // LDS broadcast
      const double hk1 = h1[k];
      const float4 wf = *(const float4*)(WHE + k*1024 + u*4);
      const float  we = WET[k*256 + u];
      const double wx = (double)wf.x, wy = (double)wf.y;
      const double wz = (double)wf.z, ww = (double)wf.w;
      const double wv = (double)we;                  // one load+cvt, two FMAs
      p0 = fma(wx, hk0, p0);  q0 = fma(wx, hk1, q0);
      p1 = fma(wy, hk0, p1);  q1 = fma(wy, hk1, q1);
      p2 = fma(wz, hk0, p2);  q2 = fma(wz, hk1, q2);
      p3 = fma(ww, hk0, p3);  q3 = fma(ww, hk1, q3);
      p4 = fma(wv, hk0, p4);  q4 = fma(wv, hk1, q4);
    }
    // deposit the OTHER batch's partials; finalize own
    if (half == 0) {
      pred[1][u][0] = q0; pred[1][u][1] = q1; pred[1][u][2] = q2;
      pred[1][u][3] = q3; pred[1][u][4] = q4;
    } else {
      pred[0][u][0] = p0; pred[0][u][1] = p1; pred[0][u][2] = p2;
      pred[0][u][3] = p3; pred[0][u][4] = p4;
    }
    __syncthreads();
    {
      const double a0 = half ? (q0 + pred[1][u][0]) : (p0 + pred[0][u][0]);
      const double a1 = half ? (q1 + pred[1][u][1]) : (p1 + pred[0][u][1]);
      const double a2 = half ? (q2 + pred[1][u][2]) : (p2 + pred[0][u][2]);
      const double a3 = half ? (q3 + pred[1][u][3]) : (p3 + pred[0][u][3]);
      const double ae = half ? (q4 + pred[1][u][4]) : (p4 + pred[0][u][4]);
      const double xg0 = half ? x10 : x00;
      const double xg1 = half ? x11 : x01;
      const double gi = a0 + fma(wxE[0], xg0, fma(wxE[1], xg1, wxE[8]));
      const double gf = a1 + fma(wxE[2], xg0, fma(wxE[3], xg1, wxE[9]));
      const double gg = a2 + fma(wxE[4], xg0, fma(wxE[5], xg1, wxE[10]));
      const double go = a3 + fma(wxE[6], xg0, fma(wxE[7], xg1, wxE[11]));
      const double cn = sigmoid_d(gf)*c_state + sigmoid_d(gi)*tanh(gg);
      const double hn = sigmoid_d(go)*tanh(cn);
      c_state = cn;
      if (t > 0) epown[(t-1)*256 + u] = ae + be_u;   // ep[t-1] = We*h^(t)+be
      hls[par ^ 1][half][u] = hn;
    }
    __syncthreads();
    par ^= 1;
  }
  // ep[99] from h^(100)
  {
    double ae0 = 0.0, ae1 = 0.0;
    const double* h0 = hls[par][0];
    const double* h1 = hls[par][1];
    #pragma unroll 4
    for (int k = k0; k < k0 + 128; ++k) {
      const double wv = (double)WET[k*256 + u];
      ae0 = fma(wv, h0[k], ae0);
      ae1 = fma(wv, h1[k], ae1);
    }
    if (half == 0) pred[1][u][0] = ae1; else pred[0][u][0] = ae0;
    __syncthreads();
    const double ae = half ? (ae1 + pred[1][u][0]) : (ae0 + pred[0][u][0]);
    epown[99*256 + u] = ae + be_u;
  }

  // ===================== decoder =====================
  unsigned long long m0 = 0ull, m1 = 0ull;   // owned batch's visited mask
  float lp_acc = 0.0f;

  for (int t = 0; t < 100; ++t) {
    // ---------- LSTM cell (k-split, both batches per thread) ----------
    {
      const double x00 = (double)s_din[0][0], x01 = (double)s_din[0][1];
      const double x10 = (double)s_din[1][0], x11 = (double)s_din[1][1];
      double p0 = 0.0, p1 = 0.0, p2 = 0.0, p3 = 0.0;
      double q0 = 0.0, q1 = 0.0, q2 = 0.0, q3 = 0.0;
      const double* h0 = hls[par][0];
      const double* h1 = hls[par][1];
      #pragma unroll 4
      for (int k = k0; k < k0 + 128; ++k) {
        const double hk0 = h0[k];
        const double hk1 = h1[k];
        const float4 wf = *(const float4*)(WHD + k*1024 + u*4);
        const double wx = (double)wf.x, wy = (double)wf.y;
        const double wz = (double)wf.z, ww = (double)wf.w;
        p0 = fma(wx, hk0, p0);  q0 = fma(wx, hk1, q0);
        p1 = fma(wy, hk0, p1);  q1 = fma(wy, hk1, q1);
        p2 = fma(wz, hk0, p2);  q2 = fma(wz, hk1, q2);
        p3 = fma(ww, hk0, p3);  q3 = fma(ww, hk1, q3);
      }
      if (half == 0) {
        pred[1][u][0] = q0; pred[1][u][1] = q1;
        pred[1][u][2] = q2; pred[1][u][3] = q3;
      } else {
        pred[0][u][0] = p0; pred[0][u][1] = p1;
        pred[0][u][2] = p2; pred[0][u][3] = p3;
      }
      __syncthreads();
      {
        const double a0 = half ? (q0 + pred[1][u][0]) : (p0 + pred[0][u][0]);
        const double a1 = half ? (q1 + pred[1][u][1]) : (p1 + pred[0][u][1]);
        const double a2 = half ? (q2 + pred[1][u][2]) : (p2 + pred[0][u][2]);
        const double a3 = half ? (q3 + pred[1][u][3]) : (p3 + pred[0][u][3]);
        const double xg0 = half ? x10 : x00;
        const double xg1 = half ? x11 : x01;
        const double gi = a0 + fma(wxD[0], xg0, fma(wxD[1], xg1, wxD[8]));
        const double gf = a1 + fma(wxD[2], xg0, fma(wxD[3], xg1, wxD[9]));
        const double gg = a2 + fma(wxD[4], xg0, fma(wxD[5], xg1, wxD[10]));
        const double go = a3 + fma(wxD[6], xg0, fma(wxD[7], xg1, wxD[11]));
        const double cn = sigmoid_d(gf)*c_state + sigmoid_d(gi)*tanh(gg);
        const double hn = sigmoid_d(go)*tanh(cn);
        c_state = cn;
        hls[par ^ 1][half][u] = hn;
      }
      __syncthreads();
      par ^= 1;
    }
    // ---------- dec_proj rows (k-split, both batches) -> LDS ----------
    {
      double ad0 = 0.0, ad1 = 0.0;
      const double* h0 = hls[par][0];
      const double* h1 = hls[par][1];
      #pragma unroll 4
      for (int k = k0; k < k0 + 128; ++k) {
        const double wv = (double)WDT[k*256 + u];
        ad0 = fma(wv, h0[k], ad0);
        ad1 = fma(wv, h1[k], ad1);
      }
      if (half == 0) pred[1][u][0] = ad1; else pred[0][u][0] = ad0;
      // compact unmasked-s list for OWN batch (branch-free popcount prefix)
      {
        const unsigned long long um0 = ~m0;
        const unsigned long long um1 = (~m1) & 0xFFFFFFFFFull;  // 36 bits
        if (u < 100) {
          bool unm; int pre;
          if (u < 64) {
            unm = ((um0 >> u) & 1ull) != 0ull;
            pre = __popcll(um0 & ((1ull << u) - 1ull));
          } else {
            const int r = u - 64;
            unm = ((um1 >> r) & 1ull) != 0ull;
            pre = __popcll(um0) + __popcll(um1 & ((1ull << r) - 1ull));
          }
          if (unm) sm[half].slist[pre] = (unsigned char)u;
        }
      }
      __syncthreads();
      const double ad = half ? (ad1 + pred[1][u][0]) : (ad0 + pred[0][u][0]);
      dls[half][u] = ad + bd_u;
    }
    __syncthreads();
    // ---------- f64-exact scores: waves 0-3 serve b0, waves 4-7 serve b1 --
    // lane covers u' = 4*lane..4*lane+3 -> one 64-lane butterfly = full sum.
    {
      const int scnt = 100 - t;
      const int bw = w >> 2;            // batch this wave serves
      const int wi = w & 3;
      const double* epb = bw ? ep1 : ep0;
      const double dpq0 = dls[bw][lane*4 + 0];
      const double dpq1 = dls[bw][lane*4 + 1];
      const double dpq2 = dls[bw][lane*4 + 2];
      const double dpq3 = dls[bw][lane*4 + 3];
      #pragma unroll 2
      for (int i = wi; i < scnt; i += 4) {
        const int s = (int)sm[bw].slist[i];
        const double* er = epb + s*256 + lane*4;
        const double2 e01 = *(const double2*)(er);
        const double2 e23 = *(const double2*)(er + 2);
        double p =        tanh_att_d(e01.x + dpq0) * vq0;
        p = __builtin_fma(tanh_att_d(e01.y + dpq1), vq1, p);
        p = __builtin_fma(tanh_att_d(e23.x + dpq2), vq2, p);
        p = __builtin_fma(tanh_att_d(e23.y + dpq3), vq3, p);
        p = wave64_sum_d(p);
        if (lane == 0) sm[bw].sredf[s] = p;
      }
      __syncthreads();
      // ---------- np-faithful fp32 log_softmax selection (FROZEN math) ----
      // executed per batch by disjoint thread groups (half owns its batch)
      if (u < 100) {
        const bool masked = (u < 64) ? (((m0 >> u) & 1ull) != 0ull)
                                     : (((m1 >> (u-64)) & 1ull) != 0ull);
        // single rounding of the exact score to fp32 (reference dtype)
        sm[half].scores[u] = masked ? -__builtin_inff()
                                    : (float)(sm[half].sredf[u] + vb0);
      }
      __syncthreads();
      if ((w & 3) == 0) {   // m = max(scores), fp32 (waves 0 and 4)
        const int bb = w >> 2;
        const float v0 = sm[bb].scores[lane];
        const float v1 = (lane < 36) ? sm[bb].scores[64 + lane]
                                     : -__builtin_inff();
        float mv = fmaxf(v0, v1);
        #pragma unroll
        for (int mm = 1; mm < 64; mm <<= 1)
          mv = fmaxf(mv, __shfl_xor(mv, mm, 64));
        if (lane == 0) sm[bb].red_m = mv;
      }
      __syncthreads();
      if (u < 100)
        sm[half].evals[u] = expf(__fsub_rn(sm[half].scores[u], sm[half].red_m));
      __syncthreads();
      if (u == 0) {   // tid 0 (b0) and tid 256 (b1) run concurrently
        // numpy pairwise_sum for n=100: 8 accumulators over 0..95,
        // combine ((r0+r1)+(r2+r3))+((r4+r5)+(r6+r7)), sequential tail 96..99
        SMem& S = sm[half];
        float rr[8];
        #pragma unroll
        for (int j = 0; j < 8; ++j) rr[j] = S.evals[j];
        for (int i = 8; i < 96; i += 8) {
          #pragma unroll
          for (int j = 0; j < 8; ++j) rr[j] = __fadd_rn(rr[j], S.evals[i + j]);
        }
        float res = __fadd_rn(
            __fadd_rn(__fadd_rn(rr[0], rr[1]), __fadd_rn(rr[2], rr[3])),
            __fadd_rn(__fadd_rn(rr[4], rr[5]), __fadd_rn(rr[6], rr[7])));
        res = __fadd_rn(res, S.evals[96]);
        res = __fadd_rn(res, S.evals[97]);
        res = __fadd_rn(res, S.evals[98]);
        res = __fadd_rn(res, S.evals[99]);
        S.red_L = logf(res);
      }
      __syncthreads();
      if ((w & 3) == 0) {   // lp = fl(fl(s-m)-L); argmax, first index on ties
        const int bb = w >> 2;
        const float m = sm[bb].red_m, L = sm[bb].red_L;
        const float lp0 = __fsub_rn(__fsub_rn(sm[bb].scores[lane], m), L);
        const float lp1 = (lane < 36)
            ? __fsub_rn(__fsub_rn(sm[bb].scores[64 + lane], m), L)
            : -__builtin_inff();
        float bv; int bi;
        if (lp0 >= lp1) { bv = lp0; bi = lane; } else { bv = lp1; bi = 64 + lane; }
        #pragma unroll
        for (int mm = 1; mm < 64; mm <<= 1) {
          const float ov = __shfl_xor(bv, mm, 64);
          const int   oi = __shfl_xor(bi, mm, 64);
          if (ov > bv || (ov == bv && oi < bi)) { bv = ov; bi = oi; }
        }
        if (lane == 0) { sm[bb].bc_sel = bi; sm[bb].bc_lp = bv; }
      }
      __syncthreads();
      const int sel = __builtin_amdgcn_readfirstlane(sm[half].bc_sel);
      lp_acc = __fadd_rn(lp_acc, sm[half].bc_lp);  // np axis-0 sum: seq fp32
      if (sel < 64) m0 |= (1ull << sel); else m1 |= (1ull << (sel - 64));
      if (tid == 0)   out[b0*100 + t] = (float)sel;
      if (tid == 256) out[b1*100 + t] = (float)sel;
      if (tid < 2)                  s_din[0][tid]     = x[(b0*100 + sel)*2 + tid];
      if (tid >= 256 && tid < 258)  s_din[1][tid-256] = x[(b1*100 + sel)*2 + (tid-256)];
      __syncthreads();
    }
  }

  // ---------------- outputs ----------------
  if (tid == 0)   out[51200 + b0] = lp_acc;
  if (tid == 256) out[51200 + b1] = lp_acc;
  out[51712 + bown*256 + u] = (float)hls[par][half][u];
}

extern "C" void kernel_launch(void* const* d_in, const int* in_sizes, int n_in,
                              void* d_out, int out_size, void* d_ws, size_t ws_size,
                              hipStream_t stream) {
  const float* x     = (const float*)d_in[0];
  const float* eWih  = (const float*)d_in[1];
  const float* eWhh  = (const float*)d_in[2];
  const float* ebih  = (const float*)d_in[3];
  const float* ebhh  = (const float*)d_in[4];
  const float* dWih  = (const float*)d_in[5];
  const float* dWhh  = (const float*)d_in[6];
  const float* dbih  = (const float*)d_in[7];
  const float* dbhh  = (const float*)d_in[8];
  const float* We    = (const float*)d_in[9];
  const float* be    = (const float*)d_in[10];
  const float* Wd    = (const float*)d_in[11];
  const float* bd    = (const float*)d_in[12];
  const float* vw    = (const float*)d_in[13];
  const float* vb    = (const float*)d_in[14];
  const float* start = (const float*)d_in[15];
  char* ws    = (char*)d_ws;
  float* outp = (float*)d_out;

  ptrnet_prep<<<dim3(512), dim3(256), 0, stream>>>(
      eWih, eWhh, ebih, ebhh, dWih, dWhh, dbih, dbhh, We, Wd, ws);

  ptrnet_main<<<dim3(256), dim3(512), 0, stream>>>(ws, x, be, bd, vw, vb,
                                                   start, outp);
}

// Round 4
// 7205.992 us; speedup vs baseline: 1.5787x; 1.0156x over previous
//
#include <hip/hip_runtime.h>

// Pointer network: encoder LSTM -> enc_proj -> decoder LSTM + attention argmax.
// B=512, S=100, D=2, H=256.
//
// NUMERICS (FROZEN since R7, absmax 7.0 <= 7.2): f64 state trajectory (h/c/
// gates/ep/dp in f64; chain ORDER may vary -- error ~1e-13 << decision gaps)
// + EXACT np-faithful fp32 log_softmax selection (single f32 rounding of
// scores, pairwise-8 sum of exps, lp=fl(fl(s-m)-L), argmax(lp) first-index,
// lp_acc sequential fp32). R16 keeps every fp32 selection op / order / tie
// rule instruction-identical; trajectory is BIT-identical to R15.
//
// R12: barrier-free blocks. R13: 1-butterfly scores + fast f64 tanh.
// R14: k-split 512-thread blocks. R15: batch-pair blocks (2 batches/block).
// R16: CRITICAL-PATH COLLAPSE. Evidence: R14 (2x waves) +3%, R15 (1/2 L2
//  traffic) +7% -> bottleneck is the per-step phase chain, not BW/occupancy.
//  (a) ONE merged 10-stream k-loop per decoder step computes dec_proj(t) AND
//      next-step LSTM partials (both need only h(t)); gate finalize after
//      selection is ~20 ops. Separate dec_proj pass + barrier round gone.
//  (b) selection condensed into wave 0 (b0) / wave 4 (b1): registers + same-
//      wave LDS (lgkmcnt fence); 5 barriers -> 2. Decoder ~10 -> 5 barriers.
//  (c) din read directly from x (uniform) -- s_din round gone.
//  (d) score loop software-pipelines next ep double2 loads over tanh chain.

#define B_WHE  0ull                       // f32 [256 k][256 u][4 g] enc Whh^T
#define B_WHD  (B_WHE + 1048576ull)       // f32 dec
#define B_WET  (B_WHD + 1048576ull)       // f32 [256 k][256 u] We^T
#define B_WDT  (B_WET + 262144ull)        // Wd^T
#define B_WXE  (B_WDT + 262144ull)        // f64 [256 u][16] Wih+bias pack
#define B_WXD  (B_WXE + 32768ull)
#define B_EP   (B_WXD + 32768ull)         // f64 [512 b][100 t][256 u] = 104.9MB

__device__ __forceinline__ double sigmoid_d(double x) {
  return 1.0 / (1.0 + exp(-x));
}

// ---------- R13 branch-free f64 tanh (attention scores only) ----------
__device__ __forceinline__ double exp_pos_d(double a) {  // a in [0, 45]
  const double L2E    = 1.4426950408889634074;
  const double LN2_HI = 6.9314718036912381649e-01;   // ln2 hi (20 low bits 0)
  const double LN2_LO = 1.9082149292705877000e-10;
  const double nf = rint(a * L2E);
  double t = __builtin_fma(-nf, LN2_HI, a);
  t = __builtin_fma(-nf, LN2_LO, t);
  double p = 2.0876756987868099e-09;                 // 1/12!
  p = __builtin_fma(p, t, 2.5052108385441720e-08);   // 1/11!
  p = __builtin_fma(p, t, 2.7557319223985888e-07);
  p = __builtin_fma(p, t, 2.7557319223985893e-06);
  p = __builtin_fma(p, t, 2.4801587301587302e-05);
  p = __builtin_fma(p, t, 1.9841269841269841e-04);
  p = __builtin_fma(p, t, 1.3888888888888889e-03);
  p = __builtin_fma(p, t, 8.3333333333333332e-03);
  p = __builtin_fma(p, t, 4.1666666666666664e-02);
  p = __builtin_fma(p, t, 1.6666666666666666e-01);
  p = __builtin_fma(p, t, 5.0e-01);
  p = __builtin_fma(p, t, 1.0);
  p = __builtin_fma(p, t, 1.0);
  return ldexp(p, (int)nf);
}

__device__ __forceinline__ double fast_div_d(double a, double b) {
  double r = __builtin_amdgcn_rcp(b);                       // ~2^-27
  r = __builtin_fma(__builtin_fma(-b, r, 1.0), r, r);       // NR -> ~2^-53
  r = __builtin_fma(__builtin_fma(-b, r, 1.0), r, r);       // NR -> ~0.5 ulp
  double q = a * r;
  q = __builtin_fma(__builtin_fma(-b, q, a), r, q);         // residual fixup
  return q;
}

__device__ __forceinline__ double tanh_att_d(double x) {
  const double ax = fmin(fabs(x), 22.0);      // tanh(22) == 1.0 in f64
  const double e  = exp_pos_d(2.0 * ax);
  const double r  = 1.0 - fast_div_d(2.0, e + 1.0);
  return copysign(r, x);
}

__device__ __forceinline__ double shfl_xor_d(double v, int m) {
  const long long l = __double_as_longlong(v);
  int lo = (int)(l & 0xffffffffll), hi = (int)(l >> 32);
  lo = __shfl_xor(lo, m, 64);
  hi = __shfl_xor(hi, m, 64);
  return __longlong_as_double(((long long)hi << 32) | (unsigned int)lo);
}

__device__ __forceinline__ double wave64_sum_d(double v) {
  #pragma unroll
  for (int m = 1; m < 64; m <<= 1) v += shfl_xor_d(v, m);
  return v;
}

struct SMem {
  double sredf[104];        // full f64 score sum per s (one butterfly)
  unsigned char slist[104]; // compact list of unmasked s
  float  evals[104];        // exp(s-m) staging for the frozen pairwise-8 sum
  float  bc_lp;
  int    bc_sel;
};

extern "C" __global__ void ptrnet_prep(
    const float* __restrict__ eWih, const float* __restrict__ eWhh,
    const float* __restrict__ ebih, const float* __restrict__ ebhh,
    const float* __restrict__ dWih, const float* __restrict__ dWhh,
    const float* __restrict__ dbih, const float* __restrict__ dbhh,
    const float* __restrict__ We,  const float* __restrict__ Wd,
    char* __restrict__ wsb)
{
  const int idx = blockIdx.x * blockDim.x + threadIdx.x;
  const int stride = gridDim.x * blockDim.x;
  float* WHE = (float*)(wsb + B_WHE);
  float* WHD = (float*)(wsb + B_WHD);
  float* WET = (float*)(wsb + B_WET);
  float* WDT = (float*)(wsb + B_WDT);
  double* WXE = (double*)(wsb + B_WXE);
  double* WXD = (double*)(wsb + B_WXD);

  // Whh^T packs: [k][u][gate] (f32 verbatim -- exact)
  for (int i = idx; i < 256*256*4; i += stride) {
    const int g = i & 3, u = (i >> 2) & 255, k = i >> 10;
    WHE[i] = eWhh[(g*256 + u)*256 + k];
    WHD[i] = dWhh[(g*256 + u)*256 + k];
  }
  // We^T / Wd^T: [k][u]
  for (int i = idx; i < 256*256; i += stride) {
    const int u = i & 255, k = i >> 8;
    WET[i] = We[u*256 + k];
    WDT[i] = Wd[u*256 + k];
  }
  // Wih + bias pack (f64): [u][16] = {i0,i1,f0,f1,g0,g1,o0,o1, bi,bf,bg,bo}
  for (int i = idx; i < 256*16; i += stride) {
    const int f = i & 15, u = i >> 4;
    double ve = 0.0, vd = 0.0;
    if (f < 8) {
      const int gg = f >> 1, d = f & 1;
      ve = (double)eWih[(gg*256+u)*2 + d];
      vd = (double)dWih[(gg*256+u)*2 + d];
    } else if (f < 12) {
      const int gg = f - 8;
      ve = (double)ebih[gg*256+u] + (double)ebhh[gg*256+u];
      vd = (double)dbih[gg*256+u] + (double)dbhh[gg*256+u];
    }
    WXE[i] = ve;
    WXD[i] = vd;
  }
}

extern "C" __global__ void __launch_bounds__(512, 2)
ptrnet_main(char* __restrict__ wsb,
            const float* __restrict__ x,
            const float* __restrict__ be,
            const float* __restrict__ bd,
            const float* __restrict__ Vw,
            const float* __restrict__ Vb,
            const float* __restrict__ start,
            float* __restrict__ out)
{
  __shared__ double hls[2][2][256];   // [parity][batch][u] h state
  __shared__ double dls[2][256];      // [batch][u] dec_proj row
  __shared__ double pred[2][256][5];  // [batch][u][stream] cross-half partials
  __shared__ SMem sm[2];              // per-batch selection state
  const int b0   = blockIdx.x * 2;    // this block serves batches b0, b1
  const int b1   = b0 + 1;
  const int tid  = threadIdx.x;
  const int u    = tid & 255;         // hidden unit
  const int half = tid >> 8;          // k-split half AND owned batch
  const int k0   = half << 7;         // own k range [k0, k0+128)
  const int lane = tid & 63;
  const int w = __builtin_amdgcn_readfirstlane(tid >> 6);   // 0..7

  const float* WHE = (const float*)(wsb + B_WHE);
  const float* WHD = (const float*)(wsb + B_WHD);
  const float* WET = (const float*)(wsb + B_WET);
  const float* WDT = (const float*)(wsb + B_WDT);
  const double* wxE = (const double*)(wsb + B_WXE) + u*16;
  const double* wxD = (const double*)(wsb + B_WXD) + u*16;
  double* ep0 = (double*)(wsb + B_EP) + (size_t)b0*25600;
  double* ep1 = (double*)(wsb + B_EP) + (size_t)b1*25600;
  double* epown = half ? ep1 : ep0;   // the ep this thread's owned batch writes
  const int bown = half ? b1 : b0;    // owned batch global index

  const double be_u = (double)be[u];
  const double bd_u = (double)bd[u];
  const double vb0  = (double)Vb[0];
  // per-lane Vw quad (u' = 4*lane + j), loop-invariant over all steps
  const double vq0 = (double)Vw[lane*4 + 0];
  const double vq1 = (double)Vw[lane*4 + 1];
  const double vq2 = (double)Vw[lane*4 + 2];
  const double vq3 = (double)Vw[lane*4 + 3];

  double c_state = 0.0;               // owned batch's c for unit u
  int par = 0;
  if (tid < 256) { hls[0][0][tid] = 0.0; hls[0][1][tid] = 0.0; }
  __syncthreads();

  // ============================ encoder ============================
  for (int t = 0; t < 100; ++t) {
    const double x00 = (double)x[(b0*100 + t)*2 + 0];
    const double x01 = (double)x[(b0*100 + t)*2 + 1];
    const double x10 = (double)x[(b1*100 + t)*2 + 0];
    const double x11 = (double)x[(b1*100 + t)*2 + 1];
    double p0 = 0.0, p1 = 0.0, p2 = 0.0, p3 = 0.0, p4 = 0.0;  // b0 partials
    double q0 = 0.0, q1 = 0.0, q2 = 0.0, q3 = 0.0, q4 = 0.0;  // b1 partials
    const double* h0 = hls[par][0];
    const double* h1 = hls[par][1];
    #pragma unroll 8
    for (int k = k0; k < k0 + 128; ++k) {
      const double hk0 = h0[k];                      // LDS broadcast
      const double hk1 = h1[k];
      const float4 wf = *(const float4*)(WHE + k*1024 + u*4);
      const float  we = WET[k*256 + u];
      const double wx = (double)wf.x, wy = (double)wf.y;
      const double wz = (double)wf.z, ww = (double)wf.w;
      const double wv = (double)we;                  // one load+cvt, two FMAs
      p0 = fma(wx, hk0, p0);  q0 = fma(wx, hk1, q0);
      p1 = fma(wy, hk0, p1);  q1 = fma(wy, hk1, q1);
      p2 = fma(wz, hk0, p2);  q2 = fma(wz, hk1, q2);
      p3 = fma(ww, hk0, p3);  q3 = fma(ww, hk1, q3);
      p4 = fma(wv, hk0, p4);  q4 = fma(wv, hk1, q4);
    }
    // deposit the OTHER batch's partials; finalize own
    if (half == 0) {
      pred[1][u][0] = q0; pred[1][u][1] = q1; pred[1][u][2] = q2;
      pred[1][u][3] = q3; pred[1][u][4] = q4;
    } else {
      pred[0][u][0] = p0; pred[0][u][1] = p1; pred[0][u][2] = p2;
      pred[0][u][3] = p3; pred[0][u][4] = p4;
    }
    __syncthreads();
    {
      const double a0 = half ? (q0 + pred[1][u][0]) : (p0 + pred[0][u][0]);
      const double a1 = half ? (q1 + pred[1][u][1]) : (p1 + pred[0][u][1]);
      const double a2 = half ? (q2 + pred[1][u][2]) : (p2 + pred[0][u][2]);
      const double a3 = half ? (q3 + pred[1][u][3]) : (p3 + pred[0][u][3]);
      const double ae = half ? (q4 + pred[1][u][4]) : (p4 + pred[0][u][4]);
      const double xg0 = half ? x10 : x00;
      const double xg1 = half ? x11 : x01;
      const double gi = a0 + fma(wxE[0], xg0, fma(wxE[1], xg1, wxE[8]));
      const double gf = a1 + fma(wxE[2], xg0, fma(wxE[3], xg1, wxE[9]));
      const double gg = a2 + fma(wxE[4], xg0, fma(wxE[5], xg1, wxE[10]));
      const double go = a3 + fma(wxE[6], xg0, fma(wxE[7], xg1, wxE[11]));
      const double cn = sigmoid_d(gf)*c_state + sigmoid_d(gi)*tanh(gg);
      const double hn = sigmoid_d(go)*tanh(cn);
      c_state = cn;
      if (t > 0) epown[(t-1)*256 + u] = ae + be_u;   // ep[t-1] = We*h^(t)+be
      hls[par ^ 1][half][u] = hn;
    }
    __syncthreads();
    par ^= 1;
  }
  // ep[99] from h^(100)
  {
    double ae0 = 0.0, ae1 = 0.0;
    const double* h0 = hls[par][0];
    const double* h1 = hls[par][1];
    #pragma unroll 8
    for (int k = k0; k < k0 + 128; ++k) {
      const double wv = (double)WET[k*256 + u];
      ae0 = fma(wv, h0[k], ae0);
      ae1 = fma(wv, h1[k], ae1);
    }
    if (half == 0) pred[1][u][0] = ae1; else pred[0][u][0] = ae0;
    __syncthreads();
    const double ae = half ? (ae1 + pred[1][u][0]) : (ae0 + pred[0][u][0]);
    epown[99*256 + u] = ae + be_u;
  }

  // ===================== decoder =====================
  unsigned long long m0 = 0ull, m1 = 0ull;   // owned batch's visited mask
  float lp_acc = 0.0f;

  // ---- prologue: LSTM(0) with din = start (h,c carry over from encoder) ----
  {
    const double sx0 = (double)start[0];
    const double sx1 = (double)start[1];
    double p0 = 0.0, p1 = 0.0, p2 = 0.0, p3 = 0.0;
    double q0 = 0.0, q1 = 0.0, q2 = 0.0, q3 = 0.0;
    const double* h0 = hls[par][0];
    const double* h1 = hls[par][1];
    #pragma unroll 8
    for (int k = k0; k < k0 + 128; ++k) {
      const double hk0 = h0[k];
      const double hk1 = h1[k];
      const float4 wf = *(const float4*)(WHD + k*1024 + u*4);
      const double wx = (double)wf.x, wy = (double)wf.y;
      const double wz = (double)wf.z, ww = (double)wf.w;
      p0 = fma(wx, hk0, p0);  q0 = fma(wx, hk1, q0);
      p1 = fma(wy, hk0, p1);  q1 = fma(wy, hk1, q1);
      p2 = fma(wz, hk0, p2);  q2 = fma(wz, hk1, q2);
      p3 = fma(ww, hk0, p3);  q3 = fma(ww, hk1, q3);
    }
    if (half == 0) {
      pred[1][u][0] = q0; pred[1][u][1] = q1;
      pred[1][u][2] = q2; pred[1][u][3] = q3;
    } else {
      pred[0][u][0] = p0; pred[0][u][1] = p1;
      pred[0][u][2] = p2; pred[0][u][3] = p3;
    }
    __syncthreads();
    {
      const double a0 = half ? (q0 + pred[1][u][0]) : (p0 + pred[0][u][0]);
      const double a1 = half ? (q1 + pred[1][u][1]) : (p1 + pred[0][u][1]);
      const double a2 = half ? (q2 + pred[1][u][2]) : (p2 + pred[0][u][2]);
      const double a3 = half ? (q3 + pred[1][u][3]) : (p3 + pred[0][u][3]);
      const double gi = a0 + fma(wxD[0], sx0, fma(wxD[1], sx1, wxD[8]));
      const double gf = a1 + fma(wxD[2], sx0, fma(wxD[3], sx1, wxD[9]));
      const double gg = a2 + fma(wxD[4], sx0, fma(wxD[5], sx1, wxD[10]));
      const double go = a3 + fma(wxD[6], sx0, fma(wxD[7], sx1, wxD[11]));
      const double cn = sigmoid_d(gf)*c_state + sigmoid_d(gi)*tanh(gg);
      const double hn = sigmoid_d(go)*tanh(cn);
      c_state = cn;
      hls[par ^ 1][half][u] = hn;
    }
    __syncthreads();
    par ^= 1;
  }

  for (int t = 0; t < 100; ++t) {
    // ---- merged k-loop over h(t): dec_proj(t) + LSTM partials for t+1 ----
    double go0, go1, go2, go3, dpo;   // own-batch survivors (regs thru select)
    {
      double p0 = 0.0, p1 = 0.0, p2 = 0.0, p3 = 0.0, pd = 0.0;  // b0
      double q0 = 0.0, q1 = 0.0, q2 = 0.0, q3 = 0.0, qd = 0.0;  // b1
      const double* h0 = hls[par][0];
      const double* h1 = hls[par][1];
      #pragma unroll 8
      for (int k = k0; k < k0 + 128; ++k) {
        const double hk0 = h0[k];
        const double hk1 = h1[k];
        const float4 wf = *(const float4*)(WHD + k*1024 + u*4);
        const float  wd = WDT[k*256 + u];
        const double wx = (double)wf.x, wy = (double)wf.y;
        const double wz = (double)wf.z, ww = (double)wf.w;
        const double wv = (double)wd;
        p0 = fma(wx, hk0, p0);  q0 = fma(wx, hk1, q0);
        p1 = fma(wy, hk0, p1);  q1 = fma(wy, hk1, q1);
        p2 = fma(wz, hk0, p2);  q2 = fma(wz, hk1, q2);
        p3 = fma(ww, hk0, p3);  q3 = fma(ww, hk1, q3);
        pd = fma(wv, hk0, pd);  qd = fma(wv, hk1, qd);
      }
      if (half == 0) {
        pred[1][u][0] = q0; pred[1][u][1] = q1; pred[1][u][2] = q2;
        pred[1][u][3] = q3; pred[1][u][4] = qd;
      } else {
        pred[0][u][0] = p0; pred[0][u][1] = p1; pred[0][u][2] = p2;
        pred[0][u][3] = p3; pred[0][u][4] = pd;
      }
      go0 = half ? q0 : p0;  go1 = half ? q1 : p1;
      go2 = half ? q2 : p2;  go3 = half ? q3 : p3;
      dpo = half ? qd : pd;
    }
    __syncthreads();                                   // bar1
    // dec_proj combine + compact unmasked-s list (own batch)
    dls[half][u] = dpo + pred[half][u][4] + bd_u;
    {
      const unsigned long long um0 = ~m0;
      const unsigned long long um1 = (~m1) & 0xFFFFFFFFFull;  // 36 bits
      if (u < 100) {
        bool unm; int pre;
        if (u < 64) {
          unm = ((um0 >> u) & 1ull) != 0ull;
          pre = __popcll(um0 & ((1ull << u) - 1ull));
        } else {
          const int r = u - 64;
          unm = ((um1 >> r) & 1ull) != 0ull;
          pre = __popcll(um0) + __popcll(um1 & ((1ull << r) - 1ull));
        }
        if (unm) sm[half].slist[pre] = (unsigned char)u;
      }
    }
    __syncthreads();                                   // bar2
    // ---- f64-exact scores: waves 0-3 b0, waves 4-7 b1; ep prefetched ----
    {
      const int scnt = 100 - t;
      const int bw = w >> 2;
      const int wi = w & 3;
      const double* epb = bw ? ep1 : ep0;
      const double dpq0 = dls[bw][lane*4 + 0];
      const double dpq1 = dls[bw][lane*4 + 1];
      const double dpq2 = dls[bw][lane*4 + 2];
      const double dpq3 = dls[bw][lane*4 + 3];
      int i = wi;
      int scur = 0;
      double2 c01, c23;
      if (i < scnt) {
        scur = (int)sm[bw].slist[i];
        const double* er = epb + scur*256 + lane*4;
        c01 = *(const double2*)(er);
        c23 = *(const double2*)(er + 2);
      }
      while (i < scnt) {
        const int inext = i + 4;
        int snext = 0;
        double2 n01 = c01, n23 = c23;
        if (inext < scnt) {                  // prefetch next iteration's ep
          snext = (int)sm[bw].slist[inext];
          const double* er = epb + snext*256 + lane*4;
          n01 = *(const double2*)(er);
          n23 = *(const double2*)(er + 2);
        }
        double p =        tanh_att_d(c01.x + dpq0) * vq0;
        p = __builtin_fma(tanh_att_d(c01.y + dpq1), vq1, p);
        p = __builtin_fma(tanh_att_d(c23.x + dpq2), vq2, p);
        p = __builtin_fma(tanh_att_d(c23.y + dpq3), vq3, p);
        p = wave64_sum_d(p);
        if (lane == 0) sm[bw].sredf[scur] = p;
        scur = snext; c01 = n01; c23 = n23; i = inext;
      }
    }
    __syncthreads();                                   // bar3
    // ---- np-faithful fp32 selection, condensed into wave 0 / wave 4 ----
    // (wave 0 <-> half 0 <-> b0; wave 4 <-> half 1 <-> b1: masks in-register)
    if ((w & 3) == 0) {
      const int bb = w >> 2;
      const bool mk0 = ((m0 >> lane) & 1ull) != 0ull;
      const bool mk1 = (lane < 36) ? (((m1 >> lane) & 1ull) != 0ull) : true;
      const int  s1i = 64 + (lane < 36 ? lane : 0);
      // single rounding of the exact score to fp32 (reference dtype)
      const float sc0 = mk0 ? -__builtin_inff()
                            : (float)(sm[bb].sredf[lane] + vb0);
      const float sc1 = mk1 ? -__builtin_inff()
                            : (float)(sm[bb].sredf[s1i] + vb0);
      // m = max(scores), fp32 -- identical fmax tree as frozen block
      float mv = fmaxf(sc0, sc1);
      #pragma unroll
      for (int mm = 1; mm < 64; mm <<= 1)
        mv = fmaxf(mv, __shfl_xor(mv, mm, 64));
      // evals = expf(s - m), staged to LDS in the frozen index layout
      const float ev0 = expf(__fsub_rn(sc0, mv));
      sm[bb].evals[lane] = ev0;
      if (lane < 36) sm[bb].evals[64 + lane] = expf(__fsub_rn(sc1, mv));
      // same-wave LDS visibility: one ds_write instr covers all lanes;
      // fence compiler + lgkm before the read-back.
      asm volatile("s_waitcnt lgkmcnt(0)" ::: "memory");
      __builtin_amdgcn_sched_barrier(0);
      // numpy pairwise_sum for n=100 (frozen): 8 accumulators over 0..95,
      // combine ((r0+r1)+(r2+r3))+((r4+r5)+(r6+r7)), sequential tail 96..99
      // (computed uniformly by all lanes of the wave -- same values)
      float rr[8];
      #pragma unroll
      for (int j = 0; j < 8; ++j) rr[j] = sm[bb].evals[j];
      for (int i = 8; i < 96; i += 8) {
        #pragma unroll
        for (int j = 0; j < 8; ++j) rr[j] = __fadd_rn(rr[j], sm[bb].evals[i + j]);
      }
      float res = __fadd_rn(
          __fadd_rn(__fadd_rn(rr[0], rr[1]), __fadd_rn(rr[2], rr[3])),
          __fadd_rn(__fadd_rn(rr[4], rr[5]), __fadd_rn(rr[6], rr[7])));
      res = __fadd_rn(res, sm[bb].evals[96]);
      res = __fadd_rn(res, sm[bb].evals[97]);
      res = __fadd_rn(res, sm[bb].evals[98]);
      res = __fadd_rn(res, sm[bb].evals[99]);
      const float L = logf(res);
      // lp = fl(fl(s - m) - L); argmax(lp), first index on ties (frozen)
      const float lp0 = __fsub_rn(__fsub_rn(sc0, mv), L);
      const float lp1 = (lane < 36)
          ? __fsub_rn(__fsub_rn(sc1, mv), L)
          : -__builtin_inff();
      float bv; int bi;
      if (lp0 >= lp1) { bv = lp0; bi = lane; } else { bv = lp1; bi = 64 + lane; }
      #pragma unroll
      for (int mm = 1; mm < 64; mm <<= 1) {
        const float ov = __shfl_xor(bv, mm, 64);
        const int   oi = __shfl_xor(bi, mm, 64);
        if (ov > bv || (ov == bv && oi < bi)) { bv = ov; bi = oi; }
      }
      if (lane == 0) { sm[bb].bc_sel = bi; sm[bb].bc_lp = bv; }
    }
    __syncthreads();                                   // bar4
    const int sel = __builtin_amdgcn_readfirstlane(sm[half].bc_sel);
    lp_acc = __fadd_rn(lp_acc, sm[half].bc_lp);  // np axis-0 sum: seq fp32
    if (sel < 64) m0 |= (1ull << sel); else m1 |= (1ull << (sel - 64));
    if (tid == 0)   out[b0*100 + t] = (float)sel;
    if (tid == 256) out[b1*100 + t] = (float)sel;
    // ---- finalize LSTM(t+1): gates = partials + Wih*din + bias ----
    if (t < 99) {
      const double xd0 = (double)x[(bown*100 + sel)*2 + 0];  // uniform load
      const double xd1 = (double)x[(bown*100 + sel)*2 + 1];
      const double a0 = go0 + pred[half][u][0];
      const double a1 = go1 + pred[half][u][1];
      const double a2 = go2 + pred[half][u][2];
      const double a3 = go3 + pred[half][u][3];
      const double gi = a0 + fma(wxD[0], xd0, fma(wxD[1], xd1, wxD[8]));
      const double gf = a1 + fma(wxD[2], xd0, fma(wxD[3], xd1, wxD[9]));
      const double gg = a2 + fma(wxD[4], xd0, fma(wxD[5], xd1, wxD[10]));
      const double go = a3 + fma(wxD[6], xd0, fma(wxD[7], xd1, wxD[11]));
      const double cn = sigmoid_d(gf)*c_state + sigmoid_d(gi)*tanh(gg);
      const double hn = sigmoid_d(go)*tanh(cn);
      c_state = cn;
      hls[par ^ 1][half][u] = hn;
      par ^= 1;
    }
    __syncthreads();                                   // bar5
  }

  // ---------------- outputs ----------------
  if (tid == 0)   out[51200 + b0] = lp_acc;
  if (tid == 256) out[51200 + b1] = lp_acc;
  out[51712 + bown*256 + u] = (float)hls[par][half][u];
}

extern "C" void kernel_launch(void* const* d_in, const int* in_sizes, int n_in,
                              void* d_out, int out_size, void* d_ws, size_t ws_size,
                              hipStream_t stream) {
  const float* x     = (const float*)d_in[0];
  const float* eWih  = (const float*)d_in[1];
  const float* eWhh  = (const float*)d_in[2];
  const float* ebih  = (const float*)d_in[3];
  const float* ebhh  = (const float*)d_in[4];
  const float* dWih  = (const float*)d_in[5];
  const float* dWhh  = (const float*)d_in[6];
  const float* dbih  = (const float*)d_in[7];
  const float* dbhh  = (const float*)d_in[8];
  const float* We    = (const float*)d_in[9];
  const float* be    = (const float*)d_in[10];
  const float* Wd    = (const float*)d_in[11];
  const float* bd    = (const float*)d_in[12];
  const float* vw    = (const float*)d_in[13];
  const float* vb    = (const float*)d_in[14];
  const float* start = (const float*)d_in[15];
  char* ws    = (char*)d_ws;
  float* outp = (float*)d_out;

  ptrnet_prep<<<dim3(512), dim3(256), 0, stream>>>(
      eWih, eWhh, ebih, ebhh, dWih, dWhh, dbih, dbhh, We, Wd, ws);

  ptrnet_main<<<dim3(256), dim3(512), 0, stream>>>(ws, x, be, bd, vw, vb,
                                                   start, outp);
}

// Round 6
// 5897.285 us; speedup vs baseline: 1.9290x; 1.2219x over previous
//
#include <hip/hip_runtime.h>

// Pointer network: encoder LSTM -> enc_proj -> decoder LSTM + attention argmax.
// B=512, S=100, D=2, H=256.
//
// NUMERICS (FROZEN since R7, absmax 7.0 <= 7.2): f64 state trajectory (h/c/
// gates/ep/dp in f64; chain ORDER may vary -- error ~1e-13 << decision gaps)
// + EXACT np-faithful fp32 log_softmax selection (single f32 rounding of
// scores, pairwise-8 sum of exps, lp=fl(fl(s-m)-L), argmax(lp) first-index,
// lp_acc sequential fp32). Selection fp32 ops byte-identical to R7-R16.
//
// R12 block-private. R13 1-butterfly scores + fast f64 tanh. R14 k-split.
// R15 batch-pair blocks. R16 merged k-loop + condensed selection (5 bar/step).
// R17: 4-WAY K-SPLIT, 1024-thread blocks (4 waves/SIMD). Evidence: issue=
//  2.7 ms, stall=4.9 ms at 2 waves/SIMD; all waves hit vmcnt together after
//  each barrier. R14's 4-wave null was confounded (2 blocks/CU = 2x L2
//  streams); the paired block at 4 waves/SIMD adds ZERO L2 traffic.
//  Thread (u=tid&255, q=tid>>8) covers 64 ks; quarters deposit partials
//  (3 slots/batch), q0 finalizes b0, q1 finalizes b1; scores over 16 waves
//  (0-7 b0, 8-15 b1); selection in waves 0 and 8 (both masks tracked
//  block-uniformly in every thread). 4-way f64 combine = blessed order class.
// R17b: resubmit after infra double-failure; added the missing __syncthreads()
//  after the ep[99] combine (pred race vs decoder-prologue deposits).

#define B_WHE  0ull                       // f32 [256 k][256 u][4 g] enc Whh^T
#define B_WHD  (B_WHE + 1048576ull)       // f32 dec
#define B_WET  (B_WHD + 1048576ull)       // f32 [256 k][256 u] We^T
#define B_WDT  (B_WET + 262144ull)        // Wd^T
#define B_WXE  (B_WDT + 262144ull)        // f64 [256 u][16] Wih+bias pack
#define B_WXD  (B_WXE + 32768ull)
#define B_EP   (B_WXD + 32768ull)         // f64 [512 b][100 t][256 u] = 104.9MB

__device__ __forceinline__ double sigmoid_d(double x) {
  return 1.0 / (1.0 + exp(-x));
}

// ---------- R13 branch-free f64 tanh (attention scores only) ----------
__device__ __forceinline__ double exp_pos_d(double a) {  // a in [0, 45]
  const double L2E    = 1.4426950408889634074;
  const double LN2_HI = 6.9314718036912381649e-01;   // ln2 hi (20 low bits 0)
  const double LN2_LO = 1.9082149292705877000e-10;
  const double nf = rint(a * L2E);
  double t = __builtin_fma(-nf, LN2_HI, a);
  t = __builtin_fma(-nf, LN2_LO, t);
  double p = 2.0876756987868099e-09;                 // 1/12!
  p = __builtin_fma(p, t, 2.5052108385441720e-08);   // 1/11!
  p = __builtin_fma(p, t, 2.7557319223985888e-07);
  p = __builtin_fma(p, t, 2.7557319223985893e-06);
  p = __builtin_fma(p, t, 2.4801587301587302e-05);
  p = __builtin_fma(p, t, 1.9841269841269841e-04);
  p = __builtin_fma(p, t, 1.3888888888888889e-03);
  p = __builtin_fma(p, t, 8.3333333333333332e-03);
  p = __builtin_fma(p, t, 4.1666666666666664e-02);
  p = __builtin_fma(p, t, 1.6666666666666666e-01);
  p = __builtin_fma(p, t, 5.0e-01);
  p = __builtin_fma(p, t, 1.0);
  p = __builtin_fma(p, t, 1.0);
  return ldexp(p, (int)nf);
}

__device__ __forceinline__ double fast_div_d(double a, double b) {
  double r = __builtin_amdgcn_rcp(b);                       // ~2^-27
  r = __builtin_fma(__builtin_fma(-b, r, 1.0), r, r);       // NR -> ~2^-53
  r = __builtin_fma(__builtin_fma(-b, r, 1.0), r, r);       // NR -> ~0.5 ulp
  double q = a * r;
  q = __builtin_fma(__builtin_fma(-b, q, a), r, q);         // residual fixup
  return q;
}

__device__ __forceinline__ double tanh_att_d(double x) {
  const double ax = fmin(fabs(x), 22.0);      // tanh(22) == 1.0 in f64
  const double e  = exp_pos_d(2.0 * ax);
  const double r  = 1.0 - fast_div_d(2.0, e + 1.0);
  return copysign(r, x);
}

__device__ __forceinline__ double shfl_xor_d(double v, int m) {
  const long long l = __double_as_longlong(v);
  int lo = (int)(l & 0xffffffffll), hi = (int)(l >> 32);
  lo = __shfl_xor(lo, m, 64);
  hi = __shfl_xor(hi, m, 64);
  return __longlong_as_double(((long long)hi << 32) | (unsigned int)lo);
}

__device__ __forceinline__ double wave64_sum_d(double v) {
  #pragma unroll
  for (int m = 1; m < 64; m <<= 1) v += shfl_xor_d(v, m);
  return v;
}

struct SMem {
  double sredf[104];        // full f64 score sum per s (one butterfly)
  unsigned char slist[104]; // compact list of unmasked s
  float  evals[104];        // exp(s-m) staging for the frozen pairwise-8 sum
  float  bc_lp;
  int    bc_sel;
};

extern "C" __global__ void ptrnet_prep(
    const float* __restrict__ eWih, const float* __restrict__ eWhh,
    const float* __restrict__ ebih, const float* __restrict__ ebhh,
    const float* __restrict__ dWih, const float* __restrict__ dWhh,
    const float* __restrict__ dbih, const float* __restrict__ dbhh,
    const float* __restrict__ We,  const float* __restrict__ Wd,
    char* __restrict__ wsb)
{
  const int idx = blockIdx.x * blockDim.x + threadIdx.x;
  const int stride = gridDim.x * blockDim.x;
  float* WHE = (float*)(wsb + B_WHE);
  float* WHD = (float*)(wsb + B_WHD);
  float* WET = (float*)(wsb + B_WET);
  float* WDT = (float*)(wsb + B_WDT);
  double* WXE = (double*)(wsb + B_WXE);
  double* WXD = (double*)(wsb + B_WXD);

  // Whh^T packs: [k][u][gate] (f32 verbatim -- exact)
  for (int i = idx; i < 256*256*4; i += stride) {
    const int g = i & 3, u = (i >> 2) & 255, k = i >> 10;
    WHE[i] = eWhh[(g*256 + u)*256 + k];
    WHD[i] = dWhh[(g*256 + u)*256 + k];
  }
  // We^T / Wd^T: [k][u]
  for (int i = idx; i < 256*256; i += stride) {
    const int u = i & 255, k = i >> 8;
    WET[i] = We[u*256 + k];
    WDT[i] = Wd[u*256 + k];
  }
  // Wih + bias pack (f64): [u][16] = {i0,i1,f0,f1,g0,g1,o0,o1, bi,bf,bg,bo}
  for (int i = idx; i < 256*16; i += stride) {
    const int f = i & 15, u = i >> 4;
    double ve = 0.0, vd = 0.0;
    if (f < 8) {
      const int gg = f >> 1, d = f & 1;
      ve = (double)eWih[(gg*256+u)*2 + d];
      vd = (double)dWih[(gg*256+u)*2 + d];
    } else if (f < 12) {
      const int gg = f - 8;
      ve = (double)ebih[gg*256+u] + (double)ebhh[gg*256+u];
      vd = (double)dbih[gg*256+u] + (double)dbhh[gg*256+u];
    }
    WXE[i] = ve;
    WXD[i] = vd;
  }
}

extern "C" __global__ void __launch_bounds__(1024, 4)
ptrnet_main(char* __restrict__ wsb,
            const float* __restrict__ x,
            const float* __restrict__ be,
            const float* __restrict__ bd,
            const float* __restrict__ Vw,
            const float* __restrict__ Vb,
            const float* __restrict__ start,
            float* __restrict__ out)
{
  __shared__ double hls[2][2][256];     // [parity][batch][u] h state
  __shared__ double dls[2][256];        // [batch][u] dec_proj row
  __shared__ double pred[2][3][256][5]; // [batch][slot][u][stream] partials
  __shared__ SMem sm[2];                // per-batch selection state
  const int b0   = blockIdx.x * 2;      // this block serves batches b0, b1
  const int b1   = b0 + 1;
  const int tid  = threadIdx.x;
  const int u    = tid & 255;           // hidden unit
  const int q    = tid >> 8;            // quarter 0..3; q<2 owns batch q
  const int k0   = q << 6;              // own k range [k0, k0+64)
  const int lane = tid & 63;
  const int w = __builtin_amdgcn_readfirstlane(tid >> 6);   // 0..15

  const float* WHE = (const float*)(wsb + B_WHE);
  const float* WHD = (const float*)(wsb + B_WHD);
  const float* WET = (const float*)(wsb + B_WET);
  const float* WDT = (const float*)(wsb + B_WDT);
  const double* wxE = (const double*)(wsb + B_WXE) + u*16;
  const double* wxD = (const double*)(wsb + B_WXD) + u*16;
  double* ep0 = (double*)(wsb + B_EP) + (size_t)b0*25600;
  double* ep1 = (double*)(wsb + B_EP) + (size_t)b1*25600;

  const double be_u = (double)be[u];
  const double bd_u = (double)bd[u];
  const double vb0  = (double)Vb[0];
  // per-lane Vw quad (u' = 4*lane + j), loop-invariant over all steps
  const double vq0 = (double)Vw[lane*4 + 0];
  const double vq1 = (double)Vw[lane*4 + 1];
  const double vq2 = (double)Vw[lane*4 + 2];
  const double vq3 = (double)Vw[lane*4 + 3];

  double c_state = 0.0;                 // owned batch's c (valid on q<2)
  int par = 0;
  if (tid < 256) { hls[0][0][tid] = 0.0; hls[0][1][tid] = 0.0; }
  __syncthreads();

  // ============================ encoder ============================
  for (int t = 0; t < 100; ++t) {
    const double x00 = (double)x[(b0*100 + t)*2 + 0];
    const double x01 = (double)x[(b0*100 + t)*2 + 1];
    const double x10 = (double)x[(b1*100 + t)*2 + 0];
    const double x11 = (double)x[(b1*100 + t)*2 + 1];
    double p0 = 0.0, p1 = 0.0, p2 = 0.0, p3 = 0.0, p4 = 0.0;  // b0 partials
    double q0 = 0.0, q1 = 0.0, q2 = 0.0, q3 = 0.0, q4 = 0.0;  // b1 partials
    const double* h0 = hls[par][0];
    const double* h1 = hls[par][1];
    #pragma unroll 8
    for (int k = k0; k < k0 + 64; ++k) {
      const double hk0 = h0[k];                      // LDS broadcast
      const double hk1 = h1[k];
      const float4 wf = *(const float4*)(WHE + k*1024 + u*4);
      const float  we = WET[k*256 + u];
      const double wx = (double)wf.x, wy = (double)wf.y;
      const double wz = (double)wf.z, ww = (double)wf.w;
      const double wv = (double)we;                  // one load+cvt, two FMAs
      p0 = fma(wx, hk0, p0);  q0 = fma(wx, hk1, q0);
      p1 = fma(wy, hk0, p1);  q1 = fma(wy, hk1, q1);
      p2 = fma(wz, hk0, p2);  q2 = fma(wz, hk1, q2);
      p3 = fma(ww, hk0, p3);  q3 = fma(ww, hk1, q3);
      p4 = fma(wv, hk0, p4);  q4 = fma(wv, hk1, q4);
    }
    if (q == 0) {
      pred[1][0][u][0] = q0; pred[1][0][u][1] = q1; pred[1][0][u][2] = q2;
      pred[1][0][u][3] = q3; pred[1][0][u][4] = q4;
    } else if (q == 1) {
      pred[0][0][u][0] = p0; pred[0][0][u][1] = p1; pred[0][0][u][2] = p2;
      pred[0][0][u][3] = p3; pred[0][0][u][4] = p4;
    } else {
      const int sl = q - 1;   // slots 1,2
      pred[0][sl][u][0] = p0; pred[0][sl][u][1] = p1; pred[0][sl][u][2] = p2;
      pred[0][sl][u][3] = p3; pred[0][sl][u][4] = p4;
      pred[1][sl][u][0] = q0; pred[1][sl][u][1] = q1; pred[1][sl][u][2] = q2;
      pred[1][sl][u][3] = q3; pred[1][sl][u][4] = q4;
    }
    __syncthreads();
    if (q < 2) {
      const double o0 = q ? q0 : p0, o1 = q ? q1 : p1, o2 = q ? q2 : p2;
      const double o3 = q ? q3 : p3, o4 = q ? q4 : p4;
      const double a0 = o0 + pred[q][0][u][0] + pred[q][1][u][0] + pred[q][2][u][0];
      const double a1 = o1 + pred[q][0][u][1] + pred[q][1][u][1] + pred[q][2][u][1];
      const double a2 = o2 + pred[q][0][u][2] + pred[q][1][u][2] + pred[q][2][u][2];
      const double a3 = o3 + pred[q][0][u][3] + pred[q][1][u][3] + pred[q][2][u][3];
      const double ae = o4 + pred[q][0][u][4] + pred[q][1][u][4] + pred[q][2][u][4];
      const double xg0 = q ? x10 : x00;
      const double xg1 = q ? x11 : x01;
      const double gi = a0 + fma(wxE[0], xg0, fma(wxE[1], xg1, wxE[8]));
      const double gf = a1 + fma(wxE[2], xg0, fma(wxE[3], xg1, wxE[9]));
      const double gg = a2 + fma(wxE[4], xg0, fma(wxE[5], xg1, wxE[10]));
      const double go = a3 + fma(wxE[6], xg0, fma(wxE[7], xg1, wxE[11]));
      const double cn = sigmoid_d(gf)*c_state + sigmoid_d(gi)*tanh(gg);
      const double hn = sigmoid_d(go)*tanh(cn);
      c_state = cn;
      if (t > 0) (q ? ep1 : ep0)[(t-1)*256 + u] = ae + be_u;
      hls[par ^ 1][q][u] = hn;
    }
    __syncthreads();
    par ^= 1;
  }
  // ep[99] from h^(100)
  {
    double ae0 = 0.0, ae1 = 0.0;
    const double* h0 = hls[par][0];
    const double* h1 = hls[par][1];
    #pragma unroll 8
    for (int k = k0; k < k0 + 64; ++k) {
      const double wv = (double)WET[k*256 + u];
      ae0 = fma(wv, h0[k], ae0);
      ae1 = fma(wv, h1[k], ae1);
    }
    if (q == 0) {
      pred[1][0][u][0] = ae1;
    } else if (q == 1) {
      pred[0][0][u][0] = ae0;
    } else {
      const int sl = q - 1;
      pred[0][sl][u][0] = ae0;
      pred[1][sl][u][0] = ae1;
    }
    __syncthreads();
    if (q < 2) {
      const double own = q ? ae1 : ae0;
      const double ae = own + pred[q][0][u][0] + pred[q][1][u][0] + pred[q][2][u][0];
      (q ? ep1 : ep0)[99*256 + u] = ae + be_u;
    }
    __syncthreads();   // R17b: fence pred reads vs decoder-prologue deposits
  }

  // ===================== decoder =====================
  // both batches' masks tracked block-uniformly in every thread
  unsigned long long ma0 = 0ull, ma1 = 0ull;   // b0 mask
  unsigned long long mb0 = 0ull, mb1 = 0ull;   // b1 mask
  float lp_acc = 0.0f;

  // ---- prologue: LSTM(0) with din = start (h,c carry over from encoder) ----
  {
    const double sx0 = (double)start[0];
    const double sx1 = (double)start[1];
    double p0 = 0.0, p1 = 0.0, p2 = 0.0, p3 = 0.0;
    double q0 = 0.0, q1 = 0.0, q2 = 0.0, q3 = 0.0;
    const double* h0 = hls[par][0];
    const double* h1 = hls[par][1];
    #pragma unroll 8
    for (int k = k0; k < k0 + 64; ++k) {
      const double hk0 = h0[k];
      const double hk1 = h1[k];
      const float4 wf = *(const float4*)(WHD + k*1024 + u*4);
      const double wx = (double)wf.x, wy = (double)wf.y;
      const double wz = (double)wf.z, ww = (double)wf.w;
      p0 = fma(wx, hk0, p0);  q0 = fma(wx, hk1, q0);
      p1 = fma(wy, hk0, p1);  q1 = fma(wy, hk1, q1);
      p2 = fma(wz, hk0, p2);  q2 = fma(wz, hk1, q2);
      p3 = fma(ww, hk0, p3);  q3 = fma(ww, hk1, q3);
    }
    if (q == 0) {
      pred[1][0][u][0] = q0; pred[1][0][u][1] = q1;
      pred[1][0][u][2] = q2; pred[1][0][u][3] = q3;
    } else if (q == 1) {
      pred[0][0][u][0] = p0; pred[0][0][u][1] = p1;
      pred[0][0][u][2] = p2; pred[0][0][u][3] = p3;
    } else {
      const int sl = q - 1;
      pred[0][sl][u][0] = p0; pred[0][sl][u][1] = p1;
      pred[0][sl][u][2] = p2; pred[0][sl][u][3] = p3;
      pred[1][sl][u][0] = q0; pred[1][sl][u][1] = q1;
      pred[1][sl][u][2] = q2; pred[1][sl][u][3] = q3;
    }
    __syncthreads();
    if (q < 2) {
      const double o0 = q ? q0 : p0, o1 = q ? q1 : p1;
      const double o2 = q ? q2 : p2, o3 = q ? q3 : p3;
      const double a0 = o0 + pred[q][0][u][0] + pred[q][1][u][0] + pred[q][2][u][0];
      const double a1 = o1 + pred[q][0][u][1] + pred[q][1][u][1] + pred[q][2][u][1];
      const double a2 = o2 + pred[q][0][u][2] + pred[q][1][u][2] + pred[q][2][u][2];
      const double a3 = o3 + pred[q][0][u][3] + pred[q][1][u][3] + pred[q][2][u][3];
      const double gi = a0 + fma(wxD[0], sx0, fma(wxD[1], sx1, wxD[8]));
      const double gf = a1 + fma(wxD[2], sx0, fma(wxD[3], sx1, wxD[9]));
      const double gg = a2 + fma(wxD[4], sx0, fma(wxD[5], sx1, wxD[10]));
      const double go = a3 + fma(wxD[6], sx0, fma(wxD[7], sx1, wxD[11]));
      const double cn = sigmoid_d(gf)*c_state + sigmoid_d(gi)*tanh(gg);
      const double hn = sigmoid_d(go)*tanh(cn);
      c_state = cn;
      hls[par ^ 1][q][u] = hn;
    }
    __syncthreads();
    par ^= 1;
  }

  for (int t = 0; t < 100; ++t) {
    // ---- merged k-loop over h(t): dec_proj(t) + LSTM partials for t+1 ----
    double go0, go1, go2, go3, dpo;   // own-batch survivors (regs thru select)
    {
      double p0 = 0.0, p1 = 0.0, p2 = 0.0, p3 = 0.0, pd = 0.0;  // b0
      double q0 = 0.0, q1 = 0.0, q2 = 0.0, q3 = 0.0, qd = 0.0;  // b1
      const double* h0 = hls[par][0];
      const double* h1 = hls[par][1];
      #pragma unroll 8
      for (int k = k0; k < k0 + 64; ++k) {
        const double hk0 = h0[k];
        const double hk1 = h1[k];
        const float4 wf = *(const float4*)(WHD + k*1024 + u*4);
        const float  wd = WDT[k*256 + u];
        const double wx = (double)wf.x, wy = (double)wf.y;
        const double wz = (double)wf.z, ww = (double)wf.w;
        const double wv = (double)wd;
        p0 = fma(wx, hk0, p0);  q0 = fma(wx, hk1, q0);
        p1 = fma(wy, hk0, p1);  q1 = fma(wy, hk1, q1);
        p2 = fma(wz, hk0, p2);  q2 = fma(wz, hk1, q2);
        p3 = fma(ww, hk0, p3);  q3 = fma(ww, hk1, q3);
        pd = fma(wv, hk0, pd);  qd = fma(wv, hk1, qd);
      }
      if (q == 0) {
        pred[1][0][u][0] = q0; pred[1][0][u][1] = q1; pred[1][0][u][2] = q2;
        pred[1][0][u][3] = q3; pred[1][0][u][4] = qd;
      } else if (q == 1) {
        pred[0][0][u][0] = p0; pred[0][0][u][1] = p1; pred[0][0][u][2] = p2;
        pred[0][0][u][3] = p3; pred[0][0][u][4] = pd;
      } else {
        const int sl = q - 1;
        pred[0][sl][u][0] = p0; pred[0][sl][u][1] = p1; pred[0][sl][u][2] = p2;
        pred[0][sl][u][3] = p3; pred[0][sl][u][4] = pd;
        pred[1][sl][u][0] = q0; pred[1][sl][u][1] = q1; pred[1][sl][u][2] = q2;
        pred[1][sl][u][3] = q3; pred[1][sl][u][4] = qd;
      }
      go0 = q ? q0 : p0;  go1 = q ? q1 : p1;
      go2 = q ? q2 : p2;  go3 = q ? q3 : p3;
      dpo = q ? qd : pd;
    }
    __syncthreads();                                   // bar1
    // dec_proj combine (owning quarters) + compact unmasked-s lists
    if (q < 2) {
      dls[q][u] = dpo + pred[q][0][u][4] + pred[q][1][u][4] + pred[q][2][u][4]
                  + bd_u;
      const unsigned long long km0 = q ? mb0 : ma0;
      const unsigned long long km1 = q ? mb1 : ma1;
      const unsigned long long um0 = ~km0;
      const unsigned long long um1 = (~km1) & 0xFFFFFFFFFull;  // 36 bits
      if (u < 100) {
        bool unm; int pre;
        if (u < 64) {
          unm = ((um0 >> u) & 1ull) != 0ull;
          pre = __popcll(um0 & ((1ull << u) - 1ull));
        } else {
          const int r = u - 64;
          unm = ((um1 >> r) & 1ull) != 0ull;
          pre = __popcll(um0) + __popcll(um1 & ((1ull << r) - 1ull));
        }
        if (unm) sm[q].slist[pre] = (unsigned char)u;
      }
    }
    __syncthreads();                                   // bar2
    // ---- f64-exact scores: waves 0-7 b0, waves 8-15 b1; ep prefetched ----
    {
      const int scnt = 100 - t;
      const int bw = w >> 3;
      const int wi = w & 7;
      const double* epb = bw ? ep1 : ep0;
      const double dpq0 = dls[bw][lane*4 + 0];
      const double dpq1 = dls[bw][lane*4 + 1];
      const double dpq2 = dls[bw][lane*4 + 2];
      const double dpq3 = dls[bw][lane*4 + 3];
      int i = wi;
      int scur = 0;
      double2 c01, c23;
      if (i < scnt) {
        scur = (int)sm[bw].slist[i];
        const double* er = epb + scur*256 + lane*4;
        c01 = *(const double2*)(er);
        c23 = *(const double2*)(er + 2);
      }
      while (i < scnt) {
        const int inext = i + 8;
        int snext = 0;
        double2 n01 = c01, n23 = c23;
        if (inext < scnt) {                  // prefetch next iteration's ep
          snext = (int)sm[bw].slist[inext];
          const double* er = epb + snext*256 + lane*4;
          n01 = *(const double2*)(er);
          n23 = *(const double2*)(er + 2);
        }
        double p =        tanh_att_d(c01.x + dpq0) * vq0;
        p = __builtin_fma(tanh_att_d(c01.y + dpq1), vq1, p);
        p = __builtin_fma(tanh_att_d(c23.x + dpq2), vq2, p);
        p = __builtin_fma(tanh_att_d(c23.y + dpq3), vq3, p);
        p = wave64_sum_d(p);
        if (lane == 0) sm[bw].sredf[scur] = p;
        scur = snext; c01 = n01; c23 = n23; i = inext;
      }
    }
    __syncthreads();                                   // bar3
    // ---- np-faithful fp32 selection, condensed into wave 0 / wave 8 ----
    if ((w & 7) == 0) {
      const int bb = w >> 3;
      const unsigned long long km0 = bb ? mb0 : ma0;
      const unsigned long long km1 = bb ? mb1 : ma1;
      const bool mk0 = ((km0 >> lane) & 1ull) != 0ull;
      const bool mk1 = (lane < 36) ? (((km1 >> lane) & 1ull) != 0ull) : true;
      const int  s1i = 64 + (lane < 36 ? lane : 0);
      // single rounding of the exact score to fp32 (reference dtype)
      const float sc0 = mk0 ? -__builtin_inff()
                            : (float)(sm[bb].sredf[lane] + vb0);
      const float sc1 = mk1 ? -__builtin_inff()
                            : (float)(sm[bb].sredf[s1i] + vb0);
      // m = max(scores), fp32 -- identical fmax tree as frozen block
      float mv = fmaxf(sc0, sc1);
      #pragma unroll
      for (int mm = 1; mm < 64; mm <<= 1)
        mv = fmaxf(mv, __shfl_xor(mv, mm, 64));
      // evals = expf(s - m), staged to LDS in the frozen index layout
      sm[bb].evals[lane] = expf(__fsub_rn(sc0, mv));
      if (lane < 36) sm[bb].evals[64 + lane] = expf(__fsub_rn(sc1, mv));
      // same-wave LDS visibility: fence compiler + lgkm before read-back
      asm volatile("s_waitcnt lgkmcnt(0)" ::: "memory");
      __builtin_amdgcn_sched_barrier(0);
      // numpy pairwise_sum for n=100 (frozen): 8 accumulators over 0..95,
      // combine ((r0+r1)+(r2+r3))+((r4+r5)+(r6+r7)), sequential tail 96..99
      float rr[8];
      #pragma unroll
      for (int j = 0; j < 8; ++j) rr[j] = sm[bb].evals[j];
      for (int i = 8; i < 96; i += 8) {
        #pragma unroll
        for (int j = 0; j < 8; ++j) rr[j] = __fadd_rn(rr[j], sm[bb].evals[i + j]);
      }
      float res = __fadd_rn(
          __fadd_rn(__fadd_rn(rr[0], rr[1]), __fadd_rn(rr[2], rr[3])),
          __fadd_rn(__fadd_rn(rr[4], rr[5]), __fadd_rn(rr[6], rr[7])));
      res = __fadd_rn(res, sm[bb].evals[96]);
      res = __fadd_rn(res, sm[bb].evals[97]);
      res = __fadd_rn(res, sm[bb].evals[98]);
      res = __fadd_rn(res, sm[bb].evals[99]);
      const float L = logf(res);
      // lp = fl(fl(s - m) - L); argmax(lp), first index on ties (frozen)
      const float lp0 = __fsub_rn(__fsub_rn(sc0, mv), L);
      const float lp1 = (lane < 36)
          ? __fsub_rn(__fsub_rn(sc1, mv), L)
          : -__builtin_inff();
      float bv; int bi;
      if (lp0 >= lp1) { bv = lp0; bi = lane; } else { bv = lp1; bi = 64 + lane; }
      #pragma unroll
      for (int mm = 1; mm < 64; mm <<= 1) {
        const float ov = __shfl_xor(bv, mm, 64);
        const int   oi = __shfl_xor(bi, mm, 64);
        if (ov > bv || (ov == bv && oi < bi)) { bv = ov; bi = oi; }
      }
      if (lane == 0) { sm[bb].bc_sel = bi; sm[bb].bc_lp = bv; }
    }
    __syncthreads();                                   // bar4
    const int sel0 = __builtin_amdgcn_readfirstlane(sm[0].bc_sel);
    const int sel1 = __builtin_amdgcn_readfirstlane(sm[1].bc_sel);
    lp_acc = __fadd_rn(lp_acc, sm[q & 1].bc_lp);  // np axis-0 sum: seq fp32
    if (sel0 < 64) ma0 |= (1ull << sel0); else ma1 |= (1ull << (sel0 - 64));
    if (sel1 < 64) mb0 |= (1ull << sel1); else mb1 |= (1ull << (sel1 - 64));
    if (tid == 0)   out[b0*100 + t] = (float)sel0;
    if (tid == 256) out[b1*100 + t] = (float)sel1;
    // ---- finalize LSTM(t+1): gates = partials + Wih*din + bias ----
    if (t < 99) {
      if (q < 2) {
        const int sel = q ? sel1 : sel0;
        const int bb  = q ? b1 : b0;
        const double xd0 = (double)x[(bb*100 + sel)*2 + 0];  // uniform load
        const double xd1 = (double)x[(bb*100 + sel)*2 + 1];
        const double a0 = go0 + pred[q][0][u][0] + pred[q][1][u][0] + pred[q][2][u][0];
        const double a1 = go1 + pred[q][0][u][1] + pred[q][1][u][1] + pred[q][2][u][1];
        const double a2 = go2 + pred[q][0][u][2] + pred[q][1][u][2] + pred[q][2][u][2];
        const double a3 = go3 + pred[q][0][u][3] + pred[q][1][u][3] + pred[q][2][u][3];
        const double gi = a0 + fma(wxD[0], xd0, fma(wxD[1], xd1, wxD[8]));
        const double gf = a1 + fma(wxD[2], xd0, fma(wxD[3], xd1, wxD[9]));
        const double gg = a2 + fma(wxD[4], xd0, fma(wxD[5], xd1, wxD[10]));
        const double go = a3 + fma(wxD[6], xd0, fma(wxD[7], xd1, wxD[11]));
        const double cn = sigmoid_d(gf)*c_state + sigmoid_d(gi)*tanh(gg);
        const double hn = sigmoid_d(go)*tanh(cn);
        c_state = cn;
        hls[par ^ 1][q][u] = hn;
      }
      par ^= 1;
    }
    __syncthreads();                                   // bar5
  }

  // ---------------- outputs ----------------
  if (tid == 0)   out[51200 + b0] = lp_acc;
  if (tid == 256) out[51200 + b1] = lp_acc;
  if (q < 2) out[51712 + (q ? b1 : b0)*256 + u] = (float)hls[par][q][u];
}

extern "C" void kernel_launch(void* const* d_in, const int* in_sizes, int n_in,
                              void* d_out, int out_size, void* d_ws, size_t ws_size,
                              hipStream_t stream) {
  const float* x     = (const float*)d_in[0];
  const float* eWih  = (const float*)d_in[1];
  const float* eWhh  = (const float*)d_in[2];
  const float* ebih  = (const float*)d_in[3];
  const float* ebhh  = (const float*)d_in[4];
  const float* dWih  = (const float*)d_in[5];
  const float* dWhh  = (const float*)d_in[6];
  const float* dbih  = (const float*)d_in[7];
  const float* dbhh  = (const float*)d_in[8];
  const float* We    = (const float*)d_in[9];
  const float* be    = (const float*)d_in[10];
  const float* Wd    = (const float*)d_in[11];
  const float* bd    = (const float*)d_in[12];
  const float* vw    = (const float*)d_in[13];
  const float* vb    = (const float*)d_in[14];
  const float* start = (const float*)d_in[15];
  char* ws    = (char*)d_ws;
  float* outp = (float*)d_out;

  ptrnet_prep<<<dim3(512), dim3(256), 0, stream>>>(
      eWih, eWhh, ebih, ebhh, dWih, dWhh, dbih, dbhh, We, Wd, ws);

  ptrnet_main<<<dim3(256), dim3(1024), 0, stream>>>(ws, x, be, bd, vw, vb,
                                                    start, outp);
}